// Round 14
// baseline (3034.598 us; speedup 1.0000x reference)
//
#include <hip/hip_runtime.h>
#include <math.h>

// Problem constants
#define B_    128
#define P_    197
#define D_    768
#define TOK_  512
#define K_    16
#define TOPK_ 8
#define L_    2
#define H_    12
#define HD_   64
#define NTOK  213            // K_ + P_
#define MROWS (B_ * NTOK)    // 27264
#define QKVN  2304           // fused q|k|v row width

typedef _Float16 f16;
typedef __attribute__((ext_vector_type(8))) _Float16 f16x8;
typedef __attribute__((ext_vector_type(4))) _Float16 f16x4;
typedef __attribute__((ext_vector_type(4))) float f32x4;

__device__ __forceinline__ void gload_lds16(const void* g, void* l) {
  __builtin_amdgcn_global_load_lds(
      (const __attribute__((address_space(1))) unsigned int*)g,
      (__attribute__((address_space(3))) unsigned int*)l, 16, 0, 0);
}

__device__ __forceinline__ float wred_sum(float v) {
#pragma unroll
  for (int o = 32; o > 0; o >>= 1) v += __shfl_xor(v, o);
  return v;
}
__device__ __forceinline__ float wred_max(float v) {
#pragma unroll
  for (int o = 32; o > 0; o >>= 1) v = fmaxf(v, __shfl_xor(v, o));
  return v;
}
__device__ __forceinline__ float red16_max(float v) {
#pragma unroll
  for (int o = 8; o > 0; o >>= 1) v = fmaxf(v, __shfl_xor(v, o));
  return v;
}
__device__ __forceinline__ float red16_sum(float v) {
#pragma unroll
  for (int o = 8; o > 0; o >>= 1) v += __shfl_xor(v, o);
  return v;
}

// ---------------- concat: x = [templates broadcast | img_patch_feats] ----
__global__ __launch_bounds__(256) void concat_kernel(
    const float* __restrict__ tpl, const float* __restrict__ patches,
    float* __restrict__ x) {
  size_t i = (size_t)blockIdx.x * 256 + threadIdx.x;  // one float4 each
  const size_t total = (size_t)MROWS * (D_ / 4);
  if (i >= total) return;
  size_t row = i / (D_ / 4);
  int c = (int)(i % (D_ / 4)) * 4;
  size_t b = row / NTOK;
  int n = (int)(row % NTOK);
  float4 v;
  if (n < K_) v = *(const float4*)(tpl + (size_t)n * D_ + c);
  else        v = *(const float4*)(patches + ((size_t)b * P_ + (n - K_)) * D_ + c);
  *(float4*)(x + row * D_ + c) = v;
}

// ---------------- LayerNorm: 4 rows/block (4 waves), f16 hi/lo out --------
__global__ __launch_bounds__(256) void ln_split_kernel(
    const float* __restrict__ x, const float* __restrict__ w,
    const float* __restrict__ b, f16* __restrict__ yh, f16* __restrict__ yl,
    int nrows) {
  int row = blockIdx.x * 4 + (threadIdx.x >> 6);
  if (row >= nrows) return;
  int lane = threadIdx.x & 63;
  const float* xr = x + (size_t)row * D_;
  float4 v[3];
#pragma unroll
  for (int j = 0; j < 3; ++j) v[j] = *(const float4*)(xr + j * 256 + lane * 4);
  float s = 0.f, sq = 0.f;
#pragma unroll
  for (int j = 0; j < 3; ++j) {
    s += v[j].x + v[j].y + v[j].z + v[j].w;
    sq = fmaf(v[j].x, v[j].x, sq); sq = fmaf(v[j].y, v[j].y, sq);
    sq = fmaf(v[j].z, v[j].z, sq); sq = fmaf(v[j].w, v[j].w, sq);
  }
#pragma unroll
  for (int o = 32; o > 0; o >>= 1) { s += __shfl_xor(s, o); sq += __shfl_xor(sq, o); }
  float mean = s * (1.f / D_);
  float var = sq * (1.f / D_) - mean * mean;
  float rs = rsqrtf(var + 1e-5f);
#pragma unroll
  for (int j = 0; j < 3; ++j) {
    int col = j * 256 + lane * 4;
    float4 wv = *(const float4*)(w + col);
    float4 bv = *(const float4*)(b + col);
    float o0 = (v[j].x - mean) * rs * wv.x + bv.x;
    float o1 = (v[j].y - mean) * rs * wv.y + bv.y;
    float o2 = (v[j].z - mean) * rs * wv.z + bv.z;
    float o3 = (v[j].w - mean) * rs * wv.w + bv.w;
    f16x4 hi = {(f16)o0, (f16)o1, (f16)o2, (f16)o3};
    f16x4 lo = {(f16)(o0 - (float)hi[0]), (f16)(o1 - (float)hi[1]),
                (f16)(o2 - (float)hi[2]), (f16)(o3 - (float)hi[3])};
    *(f16x4*)&yh[(size_t)row * D_ + col] = hi;
    *(f16x4*)&yl[(size_t)row * D_ + col] = lo;
  }
}

// -------- weight transpose + f16 hi/lo split: W[K][N] -> Wt[N][K] --------
__global__ __launch_bounds__(256) void transpose_split(
    const float* __restrict__ W, f16* __restrict__ Wh, f16* __restrict__ Wl,
    int Kd, int Nd) {
  __shared__ float t[32][33];
  const int n0 = blockIdx.x * 32, k0 = blockIdx.y * 32;
  const int tx = threadIdx.x & 31, ty = threadIdx.x >> 5;  // 32 x 8
#pragma unroll
  for (int j = 0; j < 4; ++j)
    t[ty + 8 * j][tx] = W[(size_t)(k0 + ty + 8 * j) * Nd + n0 + tx];
  __syncthreads();
#pragma unroll
  for (int j = 0; j < 4; ++j) {
    float v = t[tx][ty + 8 * j];
    f16 hi = (f16)v;
    size_t off = (size_t)(n0 + ty + 8 * j) * Kd + k0 + tx;
    Wh[off] = hi;
    Wl[off] = (f16)(v - (float)hi);
  }
}

// -------- combine q_b (768) and kv_b (1536) into qkv_b (2304) -------------
__global__ __launch_bounds__(256) void combine_bias(
    const float* __restrict__ qb, const float* __restrict__ kvb,
    float* __restrict__ out) {
  int i = blockIdx.x * 256 + threadIdx.x;
  if (i < QKVN) out[i] = (i < D_) ? qb[i] : kvb[i - D_];
}

// ------- 8-phase split-f16 MFMA GEMM (m201 template port) -----------------
// BM=BN=256, BK=32, 512 thr = 8 waves (2M x 4N, 128x64 per wave).
// LDS 2 x 64 KB dbuf (1 block/CU). Per K-step: phase0 issues 8 gloads for
// tile t+1 then counted vmcnt(8) (t+1 stays in flight all step) + barrier;
// 4 phases each {ds_read A-pair, lgkmcnt(0)+sched_barrier, setprio(1),
// 24 MFMA, setprio(0), barrier}. Band(4 N-tiles)+XCD bijective mapping.
template <int ACT, bool RESID, bool OUTSPLIT>
__global__ __launch_bounds__(512) void gemm_split8(
    const f16* __restrict__ Ah, const f16* __restrict__ Al,
    const f16* __restrict__ Wh, const f16* __restrict__ Wl,
    const float* __restrict__ bias, float* __restrict__ Cf,
    f16* __restrict__ Ch, f16* __restrict__ Cl, int M, int N, int K) {
  // per buffer (f16 units): Ah [0,8192) Al [8192,16384) Wh [16384,24576)
  // Wl [24576,32768). 2 buffers x 64 KB = 128 KB.
  __shared__ __align__(16) f16 S[2 * 32768];
  const int tid = threadIdx.x;
  // --- XCD-aware bijective chunk remap ---
  const int nwg = gridDim.x;
  const int bid = blockIdx.x;
  const int xcd = bid & 7, idx = bid >> 3;
  const int qc = nwg >> 3, rc = nwg & 7;
  const int o = (xcd < rc ? xcd * (qc + 1) : rc * (qc + 1) + (xcd - rc) * qc) + idx;
  // --- band-ordered tiles (bands of 4 N-tiles of 256, m-major inside) ---
  const int ntx = N >> 8;
  const int mt = nwg / ntx;
  const int fullArea = (ntx >> 2) * (mt << 2);
  int band, r, bw;
  if (o < fullArea) { band = o / (mt << 2); r = o - band * (mt << 2); bw = 4; }
  else             { band = ntx >> 2;      r = o - fullArea;          bw = ntx & 3; }
  const int bn = (band * 4 + r % bw) * 256;
  const int bm = (r / bw) * 256;

  const int w = tid >> 6, lane = tid & 63;
  const int wm = (w >> 2) * 128, wn = (w & 3) * 64;
  const int fr = lane & 15, kg = lane >> 4;
  const int cswz = (kg ^ ((fr >> 1) & 3)) * 8;

  f32x4 acc[8][4];
  const f32x4 z = {0.f, 0.f, 0.f, 0.f};
#pragma unroll
  for (int i = 0; i < 8; ++i)
#pragma unroll
    for (int j = 0; j < 4; ++j) acc[i][j] = z;

  auto STAGE = [&](int k0, int buf) {
    f16* base = &S[buf * 32768];
#pragma unroll
    for (int rep = 0; rep < 2; ++rep) {
      int s = tid + rep * 512;            // 0..1023
      int row = s >> 2, pch = s & 3;
      int lch = pch ^ ((row >> 1) & 3);
      int arow = bm + row; if (arow >= M) arow = M - 1;  // stores guarded
      size_t ga = (size_t)arow * K + k0 + lch * 8;
      size_t gw = (size_t)(bn + row) * K + k0 + lch * 8;
      gload_lds16(Ah + ga, base + s * 8);
      gload_lds16(Al + ga, base + 8192 + s * 8);
      gload_lds16(Wh + gw, base + 16384 + s * 8);
      gload_lds16(Wl + gw, base + 24576 + s * 8);
    }
  };

  const int nt = K / 32;
  STAGE(0, 0);
  for (int t = 0; t < nt; ++t) {
    const f16* base = &S[(t & 1) * 32768];
    if (t + 1 < nt) {
      STAGE((t + 1) * 32, (t & 1) ^ 1);
      asm volatile("s_waitcnt vmcnt(8)" ::: "memory");   // tile t landed
    } else {
      asm volatile("s_waitcnt vmcnt(0)" ::: "memory");
    }
    __builtin_amdgcn_s_barrier();
    __builtin_amdgcn_sched_barrier(0);
    // W fragments once per K-step (kept live across phases)
    f16x8 bh[4], bl[4];
#pragma unroll
    for (int nf = 0; nf < 4; ++nf) {
      int br = (wn + nf * 16 + fr) * 32 + cswz;
      bh[nf] = *(const f16x8*)(base + 16384 + br);
      bl[nf] = *(const f16x8*)(base + 24576 + br);
    }
    // 4 phases, each: ds_read A-pair -> waits -> MFMA cluster -> barrier
#pragma unroll
    for (int p = 0; p < 4; ++p) {
      f16x8 ah0, al0, ah1, al1;
      {
        int ar0 = (wm + (p * 2 + 0) * 16 + fr) * 32 + cswz;
        int ar1 = (wm + (p * 2 + 1) * 16 + fr) * 32 + cswz;
        ah0 = *(const f16x8*)(base + ar0);
        al0 = *(const f16x8*)(base + 8192 + ar0);
        ah1 = *(const f16x8*)(base + ar1);
        al1 = *(const f16x8*)(base + 8192 + ar1);
      }
      asm volatile("s_waitcnt lgkmcnt(0)" ::: "memory");
      __builtin_amdgcn_sched_barrier(0);
      __builtin_amdgcn_s_setprio(1);
#pragma unroll
      for (int nf = 0; nf < 4; ++nf) {
        acc[p * 2 + 0][nf] = __builtin_amdgcn_mfma_f32_16x16x32_f16(ah0, bh[nf], acc[p * 2 + 0][nf], 0, 0, 0);
        acc[p * 2 + 0][nf] = __builtin_amdgcn_mfma_f32_16x16x32_f16(ah0, bl[nf], acc[p * 2 + 0][nf], 0, 0, 0);
        acc[p * 2 + 0][nf] = __builtin_amdgcn_mfma_f32_16x16x32_f16(al0, bh[nf], acc[p * 2 + 0][nf], 0, 0, 0);
        acc[p * 2 + 1][nf] = __builtin_amdgcn_mfma_f32_16x16x32_f16(ah1, bh[nf], acc[p * 2 + 1][nf], 0, 0, 0);
        acc[p * 2 + 1][nf] = __builtin_amdgcn_mfma_f32_16x16x32_f16(ah1, bl[nf], acc[p * 2 + 1][nf], 0, 0, 0);
        acc[p * 2 + 1][nf] = __builtin_amdgcn_mfma_f32_16x16x32_f16(al1, bh[nf], acc[p * 2 + 1][nf], 0, 0, 0);
      }
      __builtin_amdgcn_s_setprio(0);
      __builtin_amdgcn_s_barrier();
    }
  }

  // epilogue: D[row=kg*4+rg][col=fr] per 16x16 fragment (m89 layout)
#pragma unroll
  for (int nf = 0; nf < 4; ++nf) {
    const int gc = bn + wn + nf * 16 + fr;
    const float bv = bias[gc];
#pragma unroll
    for (int mf = 0; mf < 8; ++mf) {
#pragma unroll
      for (int rg = 0; rg < 4; ++rg) {
        int gr = bm + wm + mf * 16 + kg * 4 + rg;
        if (gr < M) {
          float val = acc[mf][nf][rg] + bv;
          if (ACT == 1) val = fmaxf(val, 0.f);
          if (ACT == 2) val = 1.f / (1.f + expf(-val));
          size_t off = (size_t)gr * N + gc;
          if (OUTSPLIT) {
            f16 hi = (f16)val;
            Ch[off] = hi;
            Cl[off] = (f16)(val - (float)hi);
          } else {
            if (RESID) val += Cf[off];
            Cf[off] = val;
          }
        }
      }
    }
  }
}

// ------- small split-f16 MFMA GEMM (R11 128x128 2-phase, for att_fc) -----
template <int ACT, bool RESID, bool OUTSPLIT>
__global__ __launch_bounds__(256) void gemm_split(
    const f16* __restrict__ Ah, const f16* __restrict__ Al,
    const f16* __restrict__ Wh, const f16* __restrict__ Wl,
    const float* __restrict__ bias, float* __restrict__ Cf,
    f16* __restrict__ Ch, f16* __restrict__ Cl, int M, int N, int K) {
  __shared__ __align__(16) f16 S[2][4][128][32];
  const int tid = threadIdx.x;
  const int nwg = gridDim.x;
  const int bid = blockIdx.x;
  const int xcd = bid & 7, idx = bid >> 3;
  const int qc = nwg >> 3, rc = nwg & 7;
  const int o = (xcd < rc ? xcd * (qc + 1) : rc * (qc + 1) + (xcd - rc) * qc) + idx;
  const int ntx = N >> 7;
  const int mt = nwg / ntx;
  const int fullArea = (ntx >> 3) * (mt << 3);
  int band, r, bw;
  if (o < fullArea) { band = o / (mt << 3); r = o - band * (mt << 3); bw = 8; }
  else             { band = ntx >> 3;      r = o - fullArea;          bw = ntx & 7; }
  const int bn = (band * 8 + r % bw) * 128;
  const int bm = (r / bw) * 128;

  const int w = tid >> 6, lane = tid & 63;
  const int wm = (w & 1) * 64, wn = (w >> 1) * 64;
  const int fr = lane & 15, kg = lane >> 4;
  f32x4 acc[4][4];
  const f32x4 z = {0.f, 0.f, 0.f, 0.f};
#pragma unroll
  for (int i = 0; i < 4; ++i)
#pragma unroll
    for (int j = 0; j < 4; ++j) acc[i][j] = z;
  const int srow = tid >> 2;
  const int c_l  = (tid & 3) ^ ((tid >> 3) & 3);
  const int cswz = (kg ^ ((fr >> 1) & 3)) * 8;

  auto STAGE = [&](int k0, int buf) {
#pragma unroll
    for (int j = 0; j < 2; ++j) {
      int arow = bm + j * 64 + srow; if (arow >= M) arow = M - 1;
      int brow = bn + j * 64 + srow;
      size_t aoff = (size_t)arow * K + k0 + c_l * 8;
      size_t boff = (size_t)brow * K + k0 + c_l * 8;
      char* base = (char*)&S[buf][0][0][0] + j * 4096 + w * 1024;
      gload_lds16(Ah + aoff, base);
      gload_lds16(Al + aoff, base + 8192);
      gload_lds16(Wh + boff, base + 16384);
      gload_lds16(Wl + boff, base + 24576);
    }
  };
  auto COMPUTE = [&](int buf) {
    f16x8 ah[4], al[4], bh[4], bl[4];
#pragma unroll
    for (int i = 0; i < 4; ++i) {
      ah[i] = *(const f16x8*)&S[buf][0][wm + i * 16 + fr][cswz];
      al[i] = *(const f16x8*)&S[buf][1][wm + i * 16 + fr][cswz];
      bh[i] = *(const f16x8*)&S[buf][2][wn + i * 16 + fr][cswz];
      bl[i] = *(const f16x8*)&S[buf][3][wn + i * 16 + fr][cswz];
    }
#pragma unroll
    for (int i = 0; i < 4; ++i)
#pragma unroll
      for (int j = 0; j < 4; ++j) {
        acc[i][j] = __builtin_amdgcn_mfma_f32_16x16x32_f16(ah[i], bh[j], acc[i][j], 0, 0, 0);
        acc[i][j] = __builtin_amdgcn_mfma_f32_16x16x32_f16(ah[i], bl[j], acc[i][j], 0, 0, 0);
        acc[i][j] = __builtin_amdgcn_mfma_f32_16x16x32_f16(al[i], bh[j], acc[i][j], 0, 0, 0);
      }
  };

  const int nt = K / 32;
  int cur = 0;
  STAGE(0, 0);
  for (int t = 0; t < nt - 1; ++t) {
    STAGE((t + 1) * 32, cur ^ 1);
    asm volatile("s_waitcnt vmcnt(8)" ::: "memory");
    __builtin_amdgcn_s_barrier();
    __builtin_amdgcn_sched_barrier(0);
    COMPUTE(cur);
    __builtin_amdgcn_s_barrier();
    cur ^= 1;
  }
  asm volatile("s_waitcnt vmcnt(0)" ::: "memory");
  __builtin_amdgcn_s_barrier();
  __builtin_amdgcn_sched_barrier(0);
  COMPUTE(cur);

#pragma unroll
  for (int j = 0; j < 4; ++j) {
    const int gc = bn + wn + j * 16 + fr;
    const float bv = bias[gc];
#pragma unroll
    for (int i = 0; i < 4; ++i) {
#pragma unroll
      for (int rg = 0; rg < 4; ++rg) {
        int gr = bm + wm + i * 16 + kg * 4 + rg;
        if (gr < M) {
          float val = acc[i][j][rg] + bv;
          if (ACT == 1) val = fmaxf(val, 0.f);
          if (ACT == 2) val = 1.f / (1.f + expf(-val));
          size_t off = (size_t)gr * N + gc;
          if (OUTSPLIT) {
            f16 hi = (f16)val;
            Ch[off] = hi;
            Cl[off] = (f16)(val - (float)hi);
          } else {
            if (RESID) val += Cf[off];
            Cf[off] = val;
          }
        }
      }
    }
  }
}

// ---------------- MFMA flash attention, split-f16 3-pass ------------------
// Q/K/V read from fused qkv buffer [row][2304]: q +0, k +768, v +1536.
__global__ __launch_bounds__(256) void attn_mfma(
    const f16* __restrict__ QKVh, const f16* __restrict__ QKVl,
    f16* __restrict__ Oh, f16* __restrict__ Ol) {
  __shared__ __align__(16) f16 Ksh[64][64];
  __shared__ __align__(16) f16 Ksl[64][64];
  __shared__ __align__(16) f16 Vsh[64][64];
  __shared__ __align__(16) f16 Vsl[64][64];
  __shared__ __align__(16) f16 Psh[4][32][64];
  __shared__ __align__(16) f16 Psl[4][32][64];
  const int b = blockIdx.x, h = blockIdx.y, zb = blockIdx.z;
  const int tid = threadIdx.x, w = tid >> 6, lane = tid & 63;
  const int fr = lane & 15, kg = lane >> 4;
  const int qbase = zb * 128 + w * 32;
  const size_t rowbase = (size_t)b * NTOK;
  const int hoff = h * HD_;
  const f32x4 z4 = {0.f, 0.f, 0.f, 0.f};

  f16x8 qfh[2][2], qfl[2][2];
#pragma unroll
  for (int mf = 0; mf < 2; ++mf) {
    int qr = qbase + mf * 16 + fr; if (qr >= NTOK) qr = NTOK - 1;
    const size_t ro = (rowbase + qr) * QKVN + hoff;
#pragma unroll
    for (int ks = 0; ks < 2; ++ks) {
      qfh[mf][ks] = *(const f16x8*)&QKVh[ro + ks * 32 + kg * 8];
      qfl[mf][ks] = *(const f16x8*)&QKVl[ro + ks * 32 + kg * 8];
    }
  }

  f32x4 oacc[2][4];
#pragma unroll
  for (int mf = 0; mf < 2; ++mf)
#pragma unroll
    for (int df = 0; df < 4; ++df) oacc[mf][df] = z4;
  float m_r[2][4], l_r[2][4];
#pragma unroll
  for (int mf = 0; mf < 2; ++mf)
#pragma unroll
    for (int rg = 0; rg < 4; ++rg) { m_r[mf][rg] = -INFINITY; l_r[mf][rg] = 0.f; }

  for (int t = 0; t < 4; ++t) {
    const int t0 = t * 64;
    __syncthreads();
#pragma unroll
    for (int s = 0; s < 2; ++s) {
      int slot = tid + s * 256;
      int trow = slot >> 3, pch = slot & 7;
      int lch = pch ^ (trow & 7);
      int tok = t0 + trow; if (tok >= NTOK) tok = NTOK - 1;
      size_t src = (rowbase + tok) * (size_t)QKVN + D_ + hoff + lch * 8;
      gload_lds16(QKVh + src, (char*)&Ksh[0][0] + s * 4096 + w * 1024);
      gload_lds16(QKVl + src, (char*)&Ksl[0][0] + s * 4096 + w * 1024);
    }
    {
      int tloc = tid & 63, dg = tid >> 6;
      int tok = t0 + tloc; if (tok >= NTOK) tok = NTOK - 1;
      size_t src = (rowbase + tok) * (size_t)QKVN + 2 * D_ + hoff + dg * 16;
      f16x8 v0h = *(const f16x8*)&QKVh[src];
      f16x8 v1h = *(const f16x8*)&QKVh[src + 8];
      f16x8 v0l = *(const f16x8*)&QKVl[src];
      f16x8 v1l = *(const f16x8*)&QKVl[src + 8];
      int ch = tloc >> 3, pos = tloc & 7;
#pragma unroll
      for (int i = 0; i < 8; ++i) {
        int d0 = dg * 16 + i, d1 = d0 + 8;
        Vsh[d0][((ch ^ (d0 & 7)) << 3) | pos] = v0h[i];
        Vsh[d1][((ch ^ (d1 & 7)) << 3) | pos] = v1h[i];
        Vsl[d0][((ch ^ (d0 & 7)) << 3) | pos] = v0l[i];
        Vsl[d1][((ch ^ (d1 & 7)) << 3) | pos] = v1l[i];
      }
    }
    __syncthreads();
    f16x8 kbh[4][2], kbl[4][2];
#pragma unroll
    for (int nf = 0; nf < 4; ++nf)
#pragma unroll
      for (int ks = 0; ks < 2; ++ks) {
        int phys = (((ks * 4 + kg) ^ (fr & 7))) * 8;
        kbh[nf][ks] = *(const f16x8*)&Ksh[nf * 16 + fr][phys];
        kbl[nf][ks] = *(const f16x8*)&Ksl[nf * 16 + fr][phys];
      }
    f32x4 sacc[2][4];
#pragma unroll
    for (int mf = 0; mf < 2; ++mf)
#pragma unroll
      for (int nf = 0; nf < 4; ++nf) sacc[mf][nf] = z4;
#pragma unroll
    for (int ks = 0; ks < 2; ++ks)
#pragma unroll
      for (int mf = 0; mf < 2; ++mf)
#pragma unroll
        for (int nf = 0; nf < 4; ++nf) {
          sacc[mf][nf] = __builtin_amdgcn_mfma_f32_16x16x32_f16(qfh[mf][ks], kbh[nf][ks], sacc[mf][nf], 0, 0, 0);
          sacc[mf][nf] = __builtin_amdgcn_mfma_f32_16x16x32_f16(qfh[mf][ks], kbl[nf][ks], sacc[mf][nf], 0, 0, 0);
          sacc[mf][nf] = __builtin_amdgcn_mfma_f32_16x16x32_f16(qfl[mf][ks], kbh[nf][ks], sacc[mf][nf], 0, 0, 0);
        }
#pragma unroll
    for (int nf = 0; nf < 4; ++nf) {
      bool valid = (t0 + nf * 16 + fr) < NTOK;
#pragma unroll
      for (int mf = 0; mf < 2; ++mf)
#pragma unroll
        for (int rg = 0; rg < 4; ++rg)
          sacc[mf][nf][rg] = valid ? sacc[mf][nf][rg] * 0.125f : -INFINITY;
    }
#pragma unroll
    for (int mf = 0; mf < 2; ++mf) {
      float scl[4];
#pragma unroll
      for (int rg = 0; rg < 4; ++rg) {
        float mx = fmaxf(fmaxf(sacc[mf][0][rg], sacc[mf][1][rg]),
                         fmaxf(sacc[mf][2][rg], sacc[mf][3][rg]));
        mx = red16_max(mx);
        float nm = fmaxf(m_r[mf][rg], mx);
        scl[rg] = __expf(m_r[mf][rg] - nm);
        m_r[mf][rg] = nm;
        float ts = 0.f;
        int qlc = mf * 16 + kg * 4 + rg;
#pragma unroll
        for (int nf = 0; nf < 4; ++nf) {
          float p = __expf(sacc[mf][nf][rg] - nm);
          ts += p;
          f16 ph = (f16)p;
          int tl = nf * 16 + fr;
          int off = (((tl >> 3) ^ (qlc & 7)) << 3) | (tl & 7);
          Psh[w][qlc][off] = ph;
          Psl[w][qlc][off] = (f16)(p - (float)ph);
        }
        ts = red16_sum(ts);
        l_r[mf][rg] = l_r[mf][rg] * scl[rg] + ts;
      }
#pragma unroll
      for (int df = 0; df < 4; ++df)
#pragma unroll
        for (int rg = 0; rg < 4; ++rg)
          oacc[mf][df][rg] *= scl[rg];
    }
    f16x8 vbh[4][2], vbl[4][2];
#pragma unroll
    for (int df = 0; df < 4; ++df)
#pragma unroll
      for (int ks = 0; ks < 2; ++ks) {
        int phys = (((ks * 4 + kg) ^ (fr & 7))) * 8;
        vbh[df][ks] = *(const f16x8*)&Vsh[df * 16 + fr][phys];
        vbl[df][ks] = *(const f16x8*)&Vsl[df * 16 + fr][phys];
      }
    f16x8 pah[2][2], pal[2][2];
#pragma unroll
    for (int mf = 0; mf < 2; ++mf)
#pragma unroll
      for (int ks = 0; ks < 2; ++ks) {
        int phys = (((ks * 4 + kg) ^ (fr & 7))) * 8;
        pah[mf][ks] = *(const f16x8*)&Psh[w][mf * 16 + fr][phys];
        pal[mf][ks] = *(const f16x8*)&Psl[w][mf * 16 + fr][phys];
      }
#pragma unroll
    for (int ks = 0; ks < 2; ++ks)
#pragma unroll
      for (int mf = 0; mf < 2; ++mf)
#pragma unroll
        for (int df = 0; df < 4; ++df) {
          oacc[mf][df] = __builtin_amdgcn_mfma_f32_16x16x32_f16(pah[mf][ks], vbh[df][ks], oacc[mf][df], 0, 0, 0);
          oacc[mf][df] = __builtin_amdgcn_mfma_f32_16x16x32_f16(pah[mf][ks], vbl[df][ks], oacc[mf][df], 0, 0, 0);
          oacc[mf][df] = __builtin_amdgcn_mfma_f32_16x16x32_f16(pal[mf][ks], vbh[df][ks], oacc[mf][df], 0, 0, 0);
        }
  }
#pragma unroll
  for (int mf = 0; mf < 2; ++mf)
#pragma unroll
    for (int rg = 0; rg < 4; ++rg) {
      int qr = qbase + mf * 16 + kg * 4 + rg;
      if (qr < NTOK) {
        float inv = 1.f / l_r[mf][rg];
        size_t ro = (rowbase + qr) * D_ + hoff;
#pragma unroll
        for (int df = 0; df < 4; ++df) {
          float val = oacc[mf][df][rg] * inv;
          f16 hi = (f16)val;
          Oh[ro + df * 16 + fr] = hi;
          Ol[ro + df * 16 + fr] = (f16)(val - (float)hi);
        }
      }
    }
}

// ---------- gather x[:, :16, :] -> f16 hi/lo planes [2048][768] -----------
__global__ __launch_bounds__(256) void gather_split(
    const float* __restrict__ x, f16* __restrict__ oh, f16* __restrict__ ol) {
  int idx = blockIdx.x * 256 + threadIdx.x;
  if (idx >= B_ * K_ * (D_ / 4)) return;
  int row = idx / (D_ / 4);
  int c4 = (idx % (D_ / 4)) * 4;
  int b = row >> 4, k = row & 15;
  const float* src = x + ((size_t)(b * NTOK + k)) * D_ + c4;
  f16x4 hi, lo;
#pragma unroll
  for (int i = 0; i < 4; ++i) {
    float v = src[i];
    hi[i] = (f16)v;
    lo[i] = (f16)(v - (float)hi[i]);
  }
  *(f16x4*)&oh[(size_t)row * D_ + c4] = hi;
  *(f16x4*)&ol[(size_t)row * D_ + c4] = lo;
}

// ---------------- logits[b,k] = dot(lat[b,k,:], proj[b,:]) ----------------
__global__ __launch_bounds__(64) void logits_kernel(
    const float* __restrict__ lat, const float* __restrict__ proj,
    float* __restrict__ logits) {
  int bk = blockIdx.x;
  int b = bk >> 4;
  int lane = threadIdx.x;
  const float* lr = lat + (size_t)bk * TOK_;
  const float* pr = proj + (size_t)b * TOK_;
  float s = 0.f;
#pragma unroll
  for (int i = 0; i < 8; ++i) s = fmaf(lr[lane + 64 * i], pr[lane + 64 * i], s);
  s = wred_sum(s);
  if (lane == 0) logits[bk] = s;
}

// ---------------- softmax + topk select + normalize (1 wave per b) --------
__global__ __launch_bounds__(64) void select_kernel(
    const float* __restrict__ logits, const float* __restrict__ lat,
    float* __restrict__ out_sel, float* __restrict__ out_numr) {
  const int b = blockIdx.x;
  const int lane = threadIdx.x;
  __shared__ float aw_s[16];
  __shared__ int sel_id_s[8];
  __shared__ int numr_s;
  float v = (lane < 16) ? logits[b * 16 + lane] : -INFINITY;
  float mx = wred_max(v);
  float e = (lane < 16) ? expf(v - mx) : 0.f;
  float sum = wred_sum(e);
  float aw = e / sum;
  if (lane < 16) aw_s[lane] = aw;
  unsigned long long ball = __ballot(lane < 16 && aw > 0.05f);
  int counts = __popcll(ball);
  __syncthreads();
  if (lane == 0) {
    int num_r = counts < 1 ? 1 : (counts > TOPK_ ? TOPK_ : counts);
    numr_s = num_r;
    bool used[16];
#pragma unroll
    for (int i = 0; i < 16; ++i) used[i] = false;
    int sorted_idx[8];
    for (int j = 0; j < 8; ++j) {   // descending top-8 (ties: lowest index)
      float bv = -INFINITY; int bi = 0;
      for (int i = 0; i < 16; ++i)
        if (!used[i] && aw_s[i] > bv) { bv = aw_s[i]; bi = i; }
      used[bi] = true;
      sorted_idx[j] = bi;
    }
    int keys[8];
    for (int j = 0; j < 8; ++j) keys[j] = (j < num_r) ? sorted_idx[j] : (16 + j);
    bool kused[8];
    for (int j = 0; j < 8; ++j) kused[j] = false;
    for (int slot = 0; slot < 8; ++slot) {  // perm = argsort(keys), gather
      int bk = 1 << 30, bj = 0;
      for (int j = 0; j < 8; ++j)
        if (!kused[j] && keys[j] < bk) { bk = keys[j]; bj = j; }
      kused[bj] = true;
      sel_id_s[slot] = sorted_idx[bj];
    }
  }
  __syncthreads();
  for (int j = 0; j < 8; ++j) {
    int id = sel_id_s[j];
    const float* row = lat + ((size_t)b * 16 + id) * TOK_;
    float vals[8];
    float sq = 0.f;
#pragma unroll
    for (int i = 0; i < 8; ++i) {
      vals[i] = row[lane + 64 * i];
      sq = fmaf(vals[i], vals[i], sq);
    }
    sq = wred_sum(sq);
    float inv = 1.f / fmaxf(sqrtf(sq), 1e-12f);
#pragma unroll
    for (int i = 0; i < 8; ++i)
      out_sel[((size_t)b * 8 + j) * TOK_ + lane + 64 * i] = vals[i] * inv;
  }
  if (lane == 0) out_numr[b] = (float)numr_s;
}

// ---------------- host launcher -------------------------------------------
extern "C" void kernel_launch(void* const* d_in, const int* in_sizes, int n_in,
                              void* d_out, int out_size, void* d_ws, size_t ws_size,
                              hipStream_t stream) {
  const float* img_feature_proj = (const float*)d_in[0];
  const float* img_patch_feats  = (const float*)d_in[1];
  const float* templates        = (const float*)d_in[2];
  const float* ln1_w  = (const float*)d_in[3];
  const float* ln1_b  = (const float*)d_in[4];
  const float* q_w    = (const float*)d_in[5];
  const float* q_b    = (const float*)d_in[6];
  const float* kv_w   = (const float*)d_in[7];
  const float* kv_b   = (const float*)d_in[8];
  const float* proj_w = (const float*)d_in[9];
  const float* proj_b = (const float*)d_in[10];
  const float* ln2_w  = (const float*)d_in[11];
  const float* ln2_b  = (const float*)d_in[12];
  const float* fc1_w  = (const float*)d_in[13];
  const float* fc1_b  = (const float*)d_in[14];
  const float* fc2_w  = (const float*)d_in[15];
  const float* fc2_b  = (const float*)d_in[16];
  const float* att_fc_w = (const float*)d_in[17];
  const float* att_fc_b = (const float*)d_in[18];

  // ---- fixed workspace ----
  char* ws = (char*)d_ws;
  const size_t XB = (size_t)MROWS * D_ * 4;              // 83,755,008 B
  float* x_f = (float*)ws;  ws += XB;                    // residual fp32
  auto alloc_f16 = [&](size_t n) { f16* p = (f16*)ws; ws += n * 2; return p; };
  f16* wqkv_h = alloc_f16((size_t)QKVN * 768);
  f16* wqkv_l = alloc_f16((size_t)QKVN * 768);
  f16* wp_h   = alloc_f16((size_t)768 * 768);
  f16* wp_l   = alloc_f16((size_t)768 * 768);
  f16* wf1_h  = alloc_f16((size_t)1536 * 768);
  f16* wf1_l  = alloc_f16((size_t)1536 * 768);
  f16* wf2_h  = alloc_f16((size_t)768 * 1536);
  f16* wf2_l  = alloc_f16((size_t)768 * 1536);
  f16* awt_h  = alloc_f16((size_t)512 * 768);
  f16* awt_l  = alloc_f16((size_t)512 * 768);
  f16* lat_h  = alloc_f16((size_t)2048 * 768);
  f16* lat_l  = alloc_f16((size_t)2048 * 768);
  float* qkv_b  = (float*)ws; ws += QKVN * 4;
  float* lat    = (float*)ws; ws += (size_t)2048 * 512 * 4;
  float* logits = (float*)ws; ws += 8192;
  const size_t fixed_bytes = (size_t)(ws - (char*)d_ws);

  // ---- adaptive batch-chunk: h planes 4B + qkv planes 12B per elem-row ----
  int NB = B_;
  while (NB > 1) {
    size_t CHE = (size_t)NB * NTOK * D_;
    if (fixed_bytes + 16 * CHE <= ws_size) break;
    NB >>= 1;
  }
  const size_t CHE = (size_t)NB * NTOK * D_;
  f16* h_h   = (f16*)ws;                 // CHE
  f16* h_l   = h_h + CHE;                // CHE
  f16* qkvh  = h_l + CHE;                // 3*CHE
  f16* qkvl  = qkvh + 3 * CHE;           // 3*CHE
  f16* fc1o_h = qkvh;                    // alias: 2*CHE
  f16* fc1o_l = qkvl;                    // alias: 2*CHE

  // ---- concat ----
  {
    size_t total = (size_t)MROWS * (D_ / 4);
    concat_kernel<<<(unsigned)((total + 255) / 256), 256, 0, stream>>>(
        templates, img_patch_feats, x_f);
  }
  transpose_split<<<dim3(16, 24), 256, 0, stream>>>(att_fc_w, awt_h, awt_l, 768, 512);

  const int nchunks = B_ / NB;
  for (int l = 0; l < L_; ++l) {
    transpose_split<<<dim3(24, 24), 256, 0, stream>>>(q_w + (size_t)l * 768 * 768, wqkv_h, wqkv_l, 768, 768);
    transpose_split<<<dim3(48, 24), 256, 0, stream>>>(kv_w + (size_t)l * 768 * 1536,
        wqkv_h + (size_t)768 * 768, wqkv_l + (size_t)768 * 768, 768, 1536);
    combine_bias<<<(QKVN + 255) / 256, 256, 0, stream>>>(q_b + l * D_, kv_b + l * 1536, qkv_b);
    transpose_split<<<dim3(24, 24), 256, 0, stream>>>(proj_w + (size_t)l * 768 * 768, wp_h, wp_l, 768, 768);
    transpose_split<<<dim3(48, 24), 256, 0, stream>>>(fc1_w + (size_t)l * 768 * 1536, wf1_h, wf1_l, 768, 1536);
    transpose_split<<<dim3(24, 48), 256, 0, stream>>>(fc2_w + (size_t)l * 1536 * 768, wf2_h, wf2_l, 1536, 768);
    for (int c = 0; c < nchunks; ++c) {
      const int b0 = c * NB;
      const int Rc = NB * NTOK;
      const int mt8 = (Rc + 255) / 256;
      float* xc = x_f + (size_t)b0 * NTOK * D_;
      ln_split_kernel<<<(Rc + 3) / 4, 256, 0, stream>>>(xc, ln1_w + l * D_, ln1_b + l * D_, h_h, h_l, Rc);
      gemm_split8<0, false, true><<<(QKVN / 256) * mt8, 512, 0, stream>>>(
          h_h, h_l, wqkv_h, wqkv_l, qkv_b, nullptr, qkvh, qkvl, Rc, QKVN, 768);
      attn_mfma<<<dim3(NB, H_, 2), 256, 0, stream>>>(qkvh, qkvl, h_h, h_l);
      gemm_split8<0, true, false><<<3 * mt8, 512, 0, stream>>>(
          h_h, h_l, wp_h, wp_l, proj_b + l * D_, xc, nullptr, nullptr, Rc, 768, 768);
      ln_split_kernel<<<(Rc + 3) / 4, 256, 0, stream>>>(xc, ln2_w + l * D_, ln2_b + l * D_, h_h, h_l, Rc);
      gemm_split8<1, false, true><<<6 * mt8, 512, 0, stream>>>(
          h_h, h_l, wf1_h, wf1_l, fc1_b + l * 1536, nullptr, fc1o_h, fc1o_l, Rc, 1536, 768);
      gemm_split8<0, true, false><<<3 * mt8, 512, 0, stream>>>(
          fc1o_h, fc1o_l, wf2_h, wf2_l, fc2_b + l * D_, xc, nullptr, nullptr, Rc, 768, 1536);
    }
  }

  gather_split<<<(B_ * K_ * (D_ / 4) + 255) / 256, 256, 0, stream>>>(x_f, lat_h, lat_l);
  gemm_split<2, false, false><<<4 * 16, 256, 0, stream>>>(
      lat_h, lat_l, awt_h, awt_l, att_fc_b, lat, nullptr, nullptr, B_ * K_, TOK_, 768);

  logits_kernel<<<B_ * K_, 64, 0, stream>>>(lat, img_feature_proj, logits);
  select_kernel<<<B_, 64, 0, stream>>>(logits, lat, (float*)d_out,
                                       (float*)d_out + (size_t)B_ * TOPK_ * TOK_);
}

// Round 16
// 2698.344 us; speedup vs baseline: 1.1246x; 1.1246x over previous
//
#include <hip/hip_runtime.h>
#include <math.h>

// Problem constants
#define B_    128
#define P_    197
#define D_    768
#define TOK_  512
#define K_    16
#define TOPK_ 8
#define L_    2
#define H_    12
#define HD_   64
#define NTOK  213            // K_ + P_
#define MROWS (B_ * NTOK)    // 27264
#define QKVN  2304           // fused q|k|v row width

typedef _Float16 f16;
typedef __attribute__((ext_vector_type(8))) _Float16 f16x8;
typedef __attribute__((ext_vector_type(4))) _Float16 f16x4;
typedef __attribute__((ext_vector_type(4))) float f32x4;

__device__ __forceinline__ void gload_lds16(const void* g, void* l) {
  __builtin_amdgcn_global_load_lds(
      (const __attribute__((address_space(1))) unsigned int*)g,
      (__attribute__((address_space(3))) unsigned int*)l, 16, 0, 0);
}

__device__ __forceinline__ float wred_sum(float v) {
#pragma unroll
  for (int o = 32; o > 0; o >>= 1) v += __shfl_xor(v, o);
  return v;
}
__device__ __forceinline__ float wred_max(float v) {
#pragma unroll
  for (int o = 32; o > 0; o >>= 1) v = fmaxf(v, __shfl_xor(v, o));
  return v;
}
__device__ __forceinline__ float red16_max(float v) {
#pragma unroll
  for (int o = 8; o > 0; o >>= 1) v = fmaxf(v, __shfl_xor(v, o));
  return v;
}
__device__ __forceinline__ float red16_sum(float v) {
#pragma unroll
  for (int o = 8; o > 0; o >>= 1) v += __shfl_xor(v, o);
  return v;
}

// ---------------- concat: x = [templates broadcast | img_patch_feats] ----
__global__ __launch_bounds__(256) void concat_kernel(
    const float* __restrict__ tpl, const float* __restrict__ patches,
    float* __restrict__ x) {
  size_t i = (size_t)blockIdx.x * 256 + threadIdx.x;  // one float4 each
  const size_t total = (size_t)MROWS * (D_ / 4);
  if (i >= total) return;
  size_t row = i / (D_ / 4);
  int c = (int)(i % (D_ / 4)) * 4;
  size_t b = row / NTOK;
  int n = (int)(row % NTOK);
  float4 v;
  if (n < K_) v = *(const float4*)(tpl + (size_t)n * D_ + c);
  else        v = *(const float4*)(patches + ((size_t)b * P_ + (n - K_)) * D_ + c);
  *(float4*)(x + row * D_ + c) = v;
}

// ---------------- LayerNorm: 4 rows/block (4 waves), f16 hi/lo out --------
__global__ __launch_bounds__(256) void ln_split_kernel(
    const float* __restrict__ x, const float* __restrict__ w,
    const float* __restrict__ b, f16* __restrict__ yh, f16* __restrict__ yl,
    int nrows) {
  int row = blockIdx.x * 4 + (threadIdx.x >> 6);
  if (row >= nrows) return;
  int lane = threadIdx.x & 63;
  const float* xr = x + (size_t)row * D_;
  float4 v[3];
#pragma unroll
  for (int j = 0; j < 3; ++j) v[j] = *(const float4*)(xr + j * 256 + lane * 4);
  float s = 0.f, sq = 0.f;
#pragma unroll
  for (int j = 0; j < 3; ++j) {
    s += v[j].x + v[j].y + v[j].z + v[j].w;
    sq = fmaf(v[j].x, v[j].x, sq); sq = fmaf(v[j].y, v[j].y, sq);
    sq = fmaf(v[j].z, v[j].z, sq); sq = fmaf(v[j].w, v[j].w, sq);
  }
#pragma unroll
  for (int o = 32; o > 0; o >>= 1) { s += __shfl_xor(s, o); sq += __shfl_xor(sq, o); }
  float mean = s * (1.f / D_);
  float var = sq * (1.f / D_) - mean * mean;
  float rs = rsqrtf(var + 1e-5f);
#pragma unroll
  for (int j = 0; j < 3; ++j) {
    int col = j * 256 + lane * 4;
    float4 wv = *(const float4*)(w + col);
    float4 bv = *(const float4*)(b + col);
    float o0 = (v[j].x - mean) * rs * wv.x + bv.x;
    float o1 = (v[j].y - mean) * rs * wv.y + bv.y;
    float o2 = (v[j].z - mean) * rs * wv.z + bv.z;
    float o3 = (v[j].w - mean) * rs * wv.w + bv.w;
    f16x4 hi = {(f16)o0, (f16)o1, (f16)o2, (f16)o3};
    f16x4 lo = {(f16)(o0 - (float)hi[0]), (f16)(o1 - (float)hi[1]),
                (f16)(o2 - (float)hi[2]), (f16)(o3 - (float)hi[3])};
    *(f16x4*)&yh[(size_t)row * D_ + col] = hi;
    *(f16x4*)&yl[(size_t)row * D_ + col] = lo;
  }
}

// -------- weight transpose + f16 hi/lo split: W[K][N] -> Wt[N][K] --------
__global__ __launch_bounds__(256) void transpose_split(
    const float* __restrict__ W, f16* __restrict__ Wh, f16* __restrict__ Wl,
    int Kd, int Nd) {
  __shared__ float t[32][33];
  const int n0 = blockIdx.x * 32, k0 = blockIdx.y * 32;
  const int tx = threadIdx.x & 31, ty = threadIdx.x >> 5;  // 32 x 8
#pragma unroll
  for (int j = 0; j < 4; ++j)
    t[ty + 8 * j][tx] = W[(size_t)(k0 + ty + 8 * j) * Nd + n0 + tx];
  __syncthreads();
#pragma unroll
  for (int j = 0; j < 4; ++j) {
    float v = t[tx][ty + 8 * j];
    f16 hi = (f16)v;
    size_t off = (size_t)(n0 + ty + 8 * j) * Kd + k0 + tx;
    Wh[off] = hi;
    Wl[off] = (f16)(v - (float)hi);
  }
}

// -------- combine q_b (768) and kv_b (1536) into qkv_b (2304) -------------
__global__ __launch_bounds__(256) void combine_bias(
    const float* __restrict__ qb, const float* __restrict__ kvb,
    float* __restrict__ out) {
  int i = blockIdx.x * 256 + threadIdx.x;
  if (i < QKVN) out[i] = (i < D_) ? qb[i] : kvb[i - D_];
}

// ------- split-f16 MFMA GEMM: C = act(A @ Wt^T + bias) [+C] --------------
// R11/R13 structure (proven best): 128x128 tile, BK=32, 256 thr = 4 waves,
// 2-phase dbuf (64 KB -> 2 blocks/CU), counted vmcnt(8), chunk swizzle.
// 1D grid: XCD-chunked bijective remap (T1/m204) then band-ordered tiles
// (8 N-tiles/band, M-major inside) -> band's W-tiles L2-resident.
template <int ACT, bool RESID, bool OUTSPLIT>
__global__ __launch_bounds__(256) void gemm_split(
    const f16* __restrict__ Ah, const f16* __restrict__ Al,
    const f16* __restrict__ Wh, const f16* __restrict__ Wl,
    const float* __restrict__ bias, float* __restrict__ Cf,
    f16* __restrict__ Ch, f16* __restrict__ Cl, int M, int N, int K) {
  __shared__ __align__(16) f16 S[2][4][128][32];
  const int tid = threadIdx.x;
  // --- XCD-aware bijective chunk remap (8 XCDs, round-robin dispatch) ---
  const int nwg = gridDim.x;
  const int bid = blockIdx.x;
  const int xcd = bid & 7, idx = bid >> 3;
  const int qc = nwg >> 3, rc = nwg & 7;
  const int o = (xcd < rc ? xcd * (qc + 1) : rc * (qc + 1) + (xcd - rc) * qc) + idx;
  // --- band-ordered tile mapping (bands of 8 N-tiles, m-major inside) ---
  const int ntx = N >> 7;
  const int mt = nwg / ntx;
  const int fullArea = (ntx >> 3) * (mt << 3);
  int band, r, bw;
  if (o < fullArea) { band = o / (mt << 3); r = o - band * (mt << 3); bw = 8; }
  else             { band = ntx >> 3;      r = o - fullArea;          bw = ntx & 7; }
  const int bn = (band * 8 + r % bw) * 128;
  const int bm = (r / bw) * 128;

  const int w = tid >> 6, lane = tid & 63;
  const int wm = (w & 1) * 64, wn = (w >> 1) * 64;
  const int fr = lane & 15, kg = lane >> 4;
  f32x4 acc[4][4];
  const f32x4 z = {0.f, 0.f, 0.f, 0.f};
#pragma unroll
  for (int i = 0; i < 4; ++i)
#pragma unroll
    for (int j = 0; j < 4; ++j) acc[i][j] = z;
  const int srow = tid >> 2;
  const int c_l  = (tid & 3) ^ ((tid >> 3) & 3);
  const int cswz = (kg ^ ((fr >> 1) & 3)) * 8;

  auto STAGE = [&](int k0, int buf) {
#pragma unroll
    for (int j = 0; j < 2; ++j) {
      int arow = bm + j * 64 + srow; if (arow >= M) arow = M - 1;
      int brow = bn + j * 64 + srow;
      size_t aoff = (size_t)arow * K + k0 + c_l * 8;
      size_t boff = (size_t)brow * K + k0 + c_l * 8;
      char* base = (char*)&S[buf][0][0][0] + j * 4096 + w * 1024;
      gload_lds16(Ah + aoff, base);
      gload_lds16(Al + aoff, base + 8192);
      gload_lds16(Wh + boff, base + 16384);
      gload_lds16(Wl + boff, base + 24576);
    }
  };
  auto COMPUTE = [&](int buf) {
    f16x8 ah[4], al[4], bh[4], bl[4];
#pragma unroll
    for (int i = 0; i < 4; ++i) {
      ah[i] = *(const f16x8*)&S[buf][0][wm + i * 16 + fr][cswz];
      al[i] = *(const f16x8*)&S[buf][1][wm + i * 16 + fr][cswz];
      bh[i] = *(const f16x8*)&S[buf][2][wn + i * 16 + fr][cswz];
      bl[i] = *(const f16x8*)&S[buf][3][wn + i * 16 + fr][cswz];
    }
#pragma unroll
    for (int i = 0; i < 4; ++i)
#pragma unroll
      for (int j = 0; j < 4; ++j) {
        acc[i][j] = __builtin_amdgcn_mfma_f32_16x16x32_f16(ah[i], bh[j], acc[i][j], 0, 0, 0);
        acc[i][j] = __builtin_amdgcn_mfma_f32_16x16x32_f16(ah[i], bl[j], acc[i][j], 0, 0, 0);
        acc[i][j] = __builtin_amdgcn_mfma_f32_16x16x32_f16(al[i], bh[j], acc[i][j], 0, 0, 0);
      }
  };

  const int nt = K / 32;
  int cur = 0;
  STAGE(0, 0);
  for (int t = 0; t < nt - 1; ++t) {
    STAGE((t + 1) * 32, cur ^ 1);
    asm volatile("s_waitcnt vmcnt(8)" ::: "memory");
    __builtin_amdgcn_s_barrier();
    __builtin_amdgcn_sched_barrier(0);
    COMPUTE(cur);
    __builtin_amdgcn_s_barrier();
    cur ^= 1;
  }
  asm volatile("s_waitcnt vmcnt(0)" ::: "memory");
  __builtin_amdgcn_s_barrier();
  __builtin_amdgcn_sched_barrier(0);
  COMPUTE(cur);

#pragma unroll
  for (int j = 0; j < 4; ++j) {
    const int gc = bn + wn + j * 16 + fr;
    const float bv = bias[gc];
#pragma unroll
    for (int i = 0; i < 4; ++i) {
#pragma unroll
      for (int rg = 0; rg < 4; ++rg) {
        int gr = bm + wm + i * 16 + kg * 4 + rg;
        if (gr < M) {
          float val = acc[i][j][rg] + bv;
          if (ACT == 1) val = fmaxf(val, 0.f);
          if (ACT == 2) val = 1.f / (1.f + expf(-val));
          size_t off = (size_t)gr * N + gc;
          if (OUTSPLIT) {
            f16 hi = (f16)val;
            Ch[off] = hi;
            Cl[off] = (f16)(val - (float)hi);
          } else {
            if (RESID) val += Cf[off];
            Cf[off] = val;
          }
        }
      }
    }
  }
}

// ---------------- MFMA flash attention, split-f16 3-pass ------------------
// Q/K/V read from fused qkv buffer [row][2304]: q +0, k +768, v +1536.
__global__ __launch_bounds__(256) void attn_mfma(
    const f16* __restrict__ QKVh, const f16* __restrict__ QKVl,
    f16* __restrict__ Oh, f16* __restrict__ Ol) {
  __shared__ __align__(16) f16 Ksh[64][64];
  __shared__ __align__(16) f16 Ksl[64][64];
  __shared__ __align__(16) f16 Vsh[64][64];
  __shared__ __align__(16) f16 Vsl[64][64];
  __shared__ __align__(16) f16 Psh[4][32][64];
  __shared__ __align__(16) f16 Psl[4][32][64];
  const int b = blockIdx.x, h = blockIdx.y, zb = blockIdx.z;
  const int tid = threadIdx.x, w = tid >> 6, lane = tid & 63;
  const int fr = lane & 15, kg = lane >> 4;
  const int qbase = zb * 128 + w * 32;
  const size_t rowbase = (size_t)b * NTOK;
  const int hoff = h * HD_;
  const f32x4 z4 = {0.f, 0.f, 0.f, 0.f};

  f16x8 qfh[2][2], qfl[2][2];
#pragma unroll
  for (int mf = 0; mf < 2; ++mf) {
    int qr = qbase + mf * 16 + fr; if (qr >= NTOK) qr = NTOK - 1;
    const size_t ro = (rowbase + qr) * QKVN + hoff;
#pragma unroll
    for (int ks = 0; ks < 2; ++ks) {
      qfh[mf][ks] = *(const f16x8*)&QKVh[ro + ks * 32 + kg * 8];
      qfl[mf][ks] = *(const f16x8*)&QKVl[ro + ks * 32 + kg * 8];
    }
  }

  f32x4 oacc[2][4];
#pragma unroll
  for (int mf = 0; mf < 2; ++mf)
#pragma unroll
    for (int df = 0; df < 4; ++df) oacc[mf][df] = z4;
  float m_r[2][4], l_r[2][4];
#pragma unroll
  for (int mf = 0; mf < 2; ++mf)
#pragma unroll
    for (int rg = 0; rg < 4; ++rg) { m_r[mf][rg] = -INFINITY; l_r[mf][rg] = 0.f; }

  for (int t = 0; t < 4; ++t) {
    const int t0 = t * 64;
    __syncthreads();
#pragma unroll
    for (int s = 0; s < 2; ++s) {
      int slot = tid + s * 256;
      int trow = slot >> 3, pch = slot & 7;
      int lch = pch ^ (trow & 7);
      int tok = t0 + trow; if (tok >= NTOK) tok = NTOK - 1;
      size_t src = (rowbase + tok) * (size_t)QKVN + D_ + hoff + lch * 8;
      gload_lds16(QKVh + src, (char*)&Ksh[0][0] + s * 4096 + w * 1024);
      gload_lds16(QKVl + src, (char*)&Ksl[0][0] + s * 4096 + w * 1024);
    }
    {
      int tloc = tid & 63, dg = tid >> 6;
      int tok = t0 + tloc; if (tok >= NTOK) tok = NTOK - 1;
      size_t src = (rowbase + tok) * (size_t)QKVN + 2 * D_ + hoff + dg * 16;
      f16x8 v0h = *(const f16x8*)&QKVh[src];
      f16x8 v1h = *(const f16x8*)&QKVh[src + 8];
      f16x8 v0l = *(const f16x8*)&QKVl[src];
      f16x8 v1l = *(const f16x8*)&QKVl[src + 8];
      int ch = tloc >> 3, pos = tloc & 7;
#pragma unroll
      for (int i = 0; i < 8; ++i) {
        int d0 = dg * 16 + i, d1 = d0 + 8;
        Vsh[d0][((ch ^ (d0 & 7)) << 3) | pos] = v0h[i];
        Vsh[d1][((ch ^ (d1 & 7)) << 3) | pos] = v1h[i];
        Vsl[d0][((ch ^ (d0 & 7)) << 3) | pos] = v0l[i];
        Vsl[d1][((ch ^ (d1 & 7)) << 3) | pos] = v1l[i];
      }
    }
    __syncthreads();
    f16x8 kbh[4][2], kbl[4][2];
#pragma unroll
    for (int nf = 0; nf < 4; ++nf)
#pragma unroll
      for (int ks = 0; ks < 2; ++ks) {
        int phys = (((ks * 4 + kg) ^ (fr & 7))) * 8;
        kbh[nf][ks] = *(const f16x8*)&Ksh[nf * 16 + fr][phys];
        kbl[nf][ks] = *(const f16x8*)&Ksl[nf * 16 + fr][phys];
      }
    f32x4 sacc[2][4];
#pragma unroll
    for (int mf = 0; mf < 2; ++mf)
#pragma unroll
      for (int nf = 0; nf < 4; ++nf) sacc[mf][nf] = z4;
#pragma unroll
    for (int ks = 0; ks < 2; ++ks)
#pragma unroll
      for (int mf = 0; mf < 2; ++mf)
#pragma unroll
        for (int nf = 0; nf < 4; ++nf) {
          sacc[mf][nf] = __builtin_amdgcn_mfma_f32_16x16x32_f16(qfh[mf][ks], kbh[nf][ks], sacc[mf][nf], 0, 0, 0);
          sacc[mf][nf] = __builtin_amdgcn_mfma_f32_16x16x32_f16(qfh[mf][ks], kbl[nf][ks], sacc[mf][nf], 0, 0, 0);
          sacc[mf][nf] = __builtin_amdgcn_mfma_f32_16x16x32_f16(qfl[mf][ks], kbh[nf][ks], sacc[mf][nf], 0, 0, 0);
        }
#pragma unroll
    for (int nf = 0; nf < 4; ++nf) {
      bool valid = (t0 + nf * 16 + fr) < NTOK;
#pragma unroll
      for (int mf = 0; mf < 2; ++mf)
#pragma unroll
        for (int rg = 0; rg < 4; ++rg)
          sacc[mf][nf][rg] = valid ? sacc[mf][nf][rg] * 0.125f : -INFINITY;
    }
#pragma unroll
    for (int mf = 0; mf < 2; ++mf) {
      float scl[4];
#pragma unroll
      for (int rg = 0; rg < 4; ++rg) {
        float mx = fmaxf(fmaxf(sacc[mf][0][rg], sacc[mf][1][rg]),
                         fmaxf(sacc[mf][2][rg], sacc[mf][3][rg]));
        mx = red16_max(mx);
        float nm = fmaxf(m_r[mf][rg], mx);
        scl[rg] = __expf(m_r[mf][rg] - nm);
        m_r[mf][rg] = nm;
        float ts = 0.f;
        int qlc = mf * 16 + kg * 4 + rg;
#pragma unroll
        for (int nf = 0; nf < 4; ++nf) {
          float p = __expf(sacc[mf][nf][rg] - nm);
          ts += p;
          f16 ph = (f16)p;
          int tl = nf * 16 + fr;
          int off = (((tl >> 3) ^ (qlc & 7)) << 3) | (tl & 7);
          Psh[w][qlc][off] = ph;
          Psl[w][qlc][off] = (f16)(p - (float)ph);
        }
        ts = red16_sum(ts);
        l_r[mf][rg] = l_r[mf][rg] * scl[rg] + ts;
      }
#pragma unroll
      for (int df = 0; df < 4; ++df)
#pragma unroll
        for (int rg = 0; rg < 4; ++rg)
          oacc[mf][df][rg] *= scl[rg];
    }
    f16x8 vbh[4][2], vbl[4][2];
#pragma unroll
    for (int df = 0; df < 4; ++df)
#pragma unroll
      for (int ks = 0; ks < 2; ++ks) {
        int phys = (((ks * 4 + kg) ^ (fr & 7))) * 8;
        vbh[df][ks] = *(const f16x8*)&Vsh[df * 16 + fr][phys];
        vbl[df][ks] = *(const f16x8*)&Vsl[df * 16 + fr][phys];
      }
    f16x8 pah[2][2], pal[2][2];
#pragma unroll
    for (int mf = 0; mf < 2; ++mf)
#pragma unroll
      for (int ks = 0; ks < 2; ++ks) {
        int phys = (((ks * 4 + kg) ^ (fr & 7))) * 8;
        pah[mf][ks] = *(const f16x8*)&Psh[w][mf * 16 + fr][phys];
        pal[mf][ks] = *(const f16x8*)&Psl[w][mf * 16 + fr][phys];
      }
#pragma unroll
    for (int ks = 0; ks < 2; ++ks)
#pragma unroll
      for (int mf = 0; mf < 2; ++mf)
#pragma unroll
        for (int df = 0; df < 4; ++df) {
          oacc[mf][df] = __builtin_amdgcn_mfma_f32_16x16x32_f16(pah[mf][ks], vbh[df][ks], oacc[mf][df], 0, 0, 0);
          oacc[mf][df] = __builtin_amdgcn_mfma_f32_16x16x32_f16(pah[mf][ks], vbl[df][ks], oacc[mf][df], 0, 0, 0);
          oacc[mf][df] = __builtin_amdgcn_mfma_f32_16x16x32_f16(pal[mf][ks], vbh[df][ks], oacc[mf][df], 0, 0, 0);
        }
  }
#pragma unroll
  for (int mf = 0; mf < 2; ++mf)
#pragma unroll
    for (int rg = 0; rg < 4; ++rg) {
      int qr = qbase + mf * 16 + kg * 4 + rg;
      if (qr < NTOK) {
        float inv = 1.f / l_r[mf][rg];
        size_t ro = (rowbase + qr) * D_ + hoff;
#pragma unroll
        for (int df = 0; df < 4; ++df) {
          float val = oacc[mf][df][rg] * inv;
          f16 hi = (f16)val;
          Oh[ro + df * 16 + fr] = hi;
          Ol[ro + df * 16 + fr] = (f16)(val - (float)hi);
        }
      }
    }
}

// ---------- gather x[:, :16, :] -> f16 hi/lo planes [2048][768] -----------
__global__ __launch_bounds__(256) void gather_split(
    const float* __restrict__ x, f16* __restrict__ oh, f16* __restrict__ ol) {
  int idx = blockIdx.x * 256 + threadIdx.x;
  if (idx >= B_ * K_ * (D_ / 4)) return;
  int row = idx / (D_ / 4);
  int c4 = (idx % (D_ / 4)) * 4;
  int b = row >> 4, k = row & 15;
  const float* src = x + ((size_t)(b * NTOK + k)) * D_ + c4;
  f16x4 hi, lo;
#pragma unroll
  for (int i = 0; i < 4; ++i) {
    float v = src[i];
    hi[i] = (f16)v;
    lo[i] = (f16)(v - (float)hi[i]);
  }
  *(f16x4*)&oh[(size_t)row * D_ + c4] = hi;
  *(f16x4*)&ol[(size_t)row * D_ + c4] = lo;
}

// ---------------- logits[b,k] = dot(lat[b,k,:], proj[b,:]) ----------------
__global__ __launch_bounds__(64) void logits_kernel(
    const float* __restrict__ lat, const float* __restrict__ proj,
    float* __restrict__ logits) {
  int bk = blockIdx.x;
  int b = bk >> 4;
  int lane = threadIdx.x;
  const float* lr = lat + (size_t)bk * TOK_;
  const float* pr = proj + (size_t)b * TOK_;
  float s = 0.f;
#pragma unroll
  for (int i = 0; i < 8; ++i) s = fmaf(lr[lane + 64 * i], pr[lane + 64 * i], s);
  s = wred_sum(s);
  if (lane == 0) logits[bk] = s;
}

// ---------------- softmax + topk select + normalize (1 wave per b) --------
__global__ __launch_bounds__(64) void select_kernel(
    const float* __restrict__ logits, const float* __restrict__ lat,
    float* __restrict__ out_sel, float* __restrict__ out_numr) {
  const int b = blockIdx.x;
  const int lane = threadIdx.x;
  __shared__ float aw_s[16];
  __shared__ int sel_id_s[8];
  __shared__ int numr_s;
  float v = (lane < 16) ? logits[b * 16 + lane] : -INFINITY;
  float mx = wred_max(v);
  float e = (lane < 16) ? expf(v - mx) : 0.f;
  float sum = wred_sum(e);
  float aw = e / sum;
  if (lane < 16) aw_s[lane] = aw;
  unsigned long long ball = __ballot(lane < 16 && aw > 0.05f);
  int counts = __popcll(ball);
  __syncthreads();
  if (lane == 0) {
    int num_r = counts < 1 ? 1 : (counts > TOPK_ ? TOPK_ : counts);
    numr_s = num_r;
    bool used[16];
#pragma unroll
    for (int i = 0; i < 16; ++i) used[i] = false;
    int sorted_idx[8];
    for (int j = 0; j < 8; ++j) {   // descending top-8 (ties: lowest index)
      float bv = -INFINITY; int bi = 0;
      for (int i = 0; i < 16; ++i)
        if (!used[i] && aw_s[i] > bv) { bv = aw_s[i]; bi = i; }
      used[bi] = true;
      sorted_idx[j] = bi;
    }
    int keys[8];
    for (int j = 0; j < 8; ++j) keys[j] = (j < num_r) ? sorted_idx[j] : (16 + j);
    bool kused[8];
    for (int j = 0; j < 8; ++j) kused[j] = false;
    for (int slot = 0; slot < 8; ++slot) {  // perm = argsort(keys), gather
      int bk = 1 << 30, bj = 0;
      for (int j = 0; j < 8; ++j)
        if (!kused[j] && keys[j] < bk) { bk = keys[j]; bj = j; }
      kused[bj] = true;
      sel_id_s[slot] = sorted_idx[bj];
    }
  }
  __syncthreads();
  for (int j = 0; j < 8; ++j) {
    int id = sel_id_s[j];
    const float* row = lat + ((size_t)b * 16 + id) * TOK_;
    float vals[8];
    float sq = 0.f;
#pragma unroll
    for (int i = 0; i < 8; ++i) {
      vals[i] = row[lane + 64 * i];
      sq = fmaf(vals[i], vals[i], sq);
    }
    sq = wred_sum(sq);
    float inv = 1.f / fmaxf(sqrtf(sq), 1e-12f);
#pragma unroll
    for (int i = 0; i < 8; ++i)
      out_sel[((size_t)b * 8 + j) * TOK_ + lane + 64 * i] = vals[i] * inv;
  }
  if (lane == 0) out_numr[b] = (float)numr_s;
}

// ---------------- host launcher -------------------------------------------
extern "C" void kernel_launch(void* const* d_in, const int* in_sizes, int n_in,
                              void* d_out, int out_size, void* d_ws, size_t ws_size,
                              hipStream_t stream) {
  const float* img_feature_proj = (const float*)d_in[0];
  const float* img_patch_feats  = (const float*)d_in[1];
  const float* templates        = (const float*)d_in[2];
  const float* ln1_w  = (const float*)d_in[3];
  const float* ln1_b  = (const float*)d_in[4];
  const float* q_w    = (const float*)d_in[5];
  const float* q_b    = (const float*)d_in[6];
  const float* kv_w   = (const float*)d_in[7];
  const float* kv_b   = (const float*)d_in[8];
  const float* proj_w = (const float*)d_in[9];
  const float* proj_b = (const float*)d_in[10];
  const float* ln2_w  = (const float*)d_in[11];
  const float* ln2_b  = (const float*)d_in[12];
  const float* fc1_w  = (const float*)d_in[13];
  const float* fc1_b  = (const float*)d_in[14];
  const float* fc2_w  = (const float*)d_in[15];
  const float* fc2_b  = (const float*)d_in[16];
  const float* att_fc_w = (const float*)d_in[17];
  const float* att_fc_b = (const float*)d_in[18];

  // ---- fixed workspace ----
  char* ws = (char*)d_ws;
  const size_t XB = (size_t)MROWS * D_ * 4;              // 83,755,008 B
  float* x_f = (float*)ws;  ws += XB;                    // residual fp32
  auto alloc_f16 = [&](size_t n) { f16* p = (f16*)ws; ws += n * 2; return p; };
  f16* wqkv_h = alloc_f16((size_t)QKVN * 768);
  f16* wqkv_l = alloc_f16((size_t)QKVN * 768);
  f16* wp_h   = alloc_f16((size_t)768 * 768);
  f16* wp_l   = alloc_f16((size_t)768 * 768);
  f16* wf1_h  = alloc_f16((size_t)1536 * 768);
  f16* wf1_l  = alloc_f16((size_t)1536 * 768);
  f16* wf2_h  = alloc_f16((size_t)768 * 1536);
  f16* wf2_l  = alloc_f16((size_t)768 * 1536);
  f16* awt_h  = alloc_f16((size_t)512 * 768);
  f16* awt_l  = alloc_f16((size_t)512 * 768);
  f16* lat_h  = alloc_f16((size_t)2048 * 768);
  f16* lat_l  = alloc_f16((size_t)2048 * 768);
  float* qkv_b  = (float*)ws; ws += QKVN * 4;
  float* lat    = (float*)ws; ws += (size_t)2048 * 512 * 4;
  float* logits = (float*)ws; ws += 8192;
  const size_t fixed_bytes = (size_t)(ws - (char*)d_ws);

  // ---- adaptive batch-chunk: h planes 4B + qkv planes 12B per elem-row ----
  int NB = B_;
  while (NB > 1) {
    size_t CHE = (size_t)NB * NTOK * D_;
    if (fixed_bytes + 16 * CHE <= ws_size) break;
    NB >>= 1;
  }
  const size_t CHE = (size_t)NB * NTOK * D_;
  f16* h_h   = (f16*)ws;                 // CHE
  f16* h_l   = h_h + CHE;                // CHE
  f16* qkvh  = h_l + CHE;                // 3*CHE
  f16* qkvl  = qkvh + 3 * CHE;           // 3*CHE
  f16* fc1o_h = qkvh;                    // alias: 2*CHE
  f16* fc1o_l = qkvl;                    // alias: 2*CHE

  // ---- concat ----
  {
    size_t total = (size_t)MROWS * (D_ / 4);
    concat_kernel<<<(unsigned)((total + 255) / 256), 256, 0, stream>>>(
        templates, img_patch_feats, x_f);
  }
  transpose_split<<<dim3(16, 24), 256, 0, stream>>>(att_fc_w, awt_h, awt_l, 768, 512);

  const int nchunks = B_ / NB;
  for (int l = 0; l < L_; ++l) {
    transpose_split<<<dim3(24, 24), 256, 0, stream>>>(q_w + (size_t)l * 768 * 768, wqkv_h, wqkv_l, 768, 768);
    transpose_split<<<dim3(48, 24), 256, 0, stream>>>(kv_w + (size_t)l * 768 * 1536,
        wqkv_h + (size_t)768 * 768, wqkv_l + (size_t)768 * 768, 768, 1536);
    combine_bias<<<(QKVN + 255) / 256, 256, 0, stream>>>(q_b + l * D_, kv_b + l * 1536, qkv_b);
    transpose_split<<<dim3(24, 24), 256, 0, stream>>>(proj_w + (size_t)l * 768 * 768, wp_h, wp_l, 768, 768);
    transpose_split<<<dim3(48, 24), 256, 0, stream>>>(fc1_w + (size_t)l * 768 * 1536, wf1_h, wf1_l, 768, 1536);
    transpose_split<<<dim3(24, 48), 256, 0, stream>>>(fc2_w + (size_t)l * 1536 * 768, wf2_h, wf2_l, 1536, 768);
    for (int c = 0; c < nchunks; ++c) {
      const int b0 = c * NB;
      const int Rc = NB * NTOK;
      const int mt = (Rc + 127) / 128;
      float* xc = x_f + (size_t)b0 * NTOK * D_;
      ln_split_kernel<<<(Rc + 3) / 4, 256, 0, stream>>>(xc, ln1_w + l * D_, ln1_b + l * D_, h_h, h_l, Rc);
      gemm_split<0, false, true><<<(QKVN / 128) * mt, 256, 0, stream>>>(
          h_h, h_l, wqkv_h, wqkv_l, qkv_b, nullptr, qkvh, qkvl, Rc, QKVN, 768);
      attn_mfma<<<dim3(NB, H_, 2), 256, 0, stream>>>(qkvh, qkvl, h_h, h_l);
      gemm_split<0, true, false><<<6 * mt, 256, 0, stream>>>(
          h_h, h_l, wp_h, wp_l, proj_b + l * D_, xc, nullptr, nullptr, Rc, 768, 768);
      ln_split_kernel<<<(Rc + 3) / 4, 256, 0, stream>>>(xc, ln2_w + l * D_, ln2_b + l * D_, h_h, h_l, Rc);
      gemm_split<1, false, true><<<12 * mt, 256, 0, stream>>>(
          h_h, h_l, wf1_h, wf1_l, fc1_b + l * 1536, nullptr, fc1o_h, fc1o_l, Rc, 1536, 768);
      gemm_split<0, true, false><<<6 * mt, 256, 0, stream>>>(
          fc1o_h, fc1o_l, wf2_h, wf2_l, fc2_b + l * D_, xc, nullptr, nullptr, Rc, 768, 1536);
    }
  }

  gather_split<<<(B_ * K_ * (D_ / 4) + 255) / 256, 256, 0, stream>>>(x_f, lat_h, lat_l);
  gemm_split<2, false, false><<<4 * 16, 256, 0, stream>>>(
      lat_h, lat_l, awt_h, awt_l, att_fc_b, lat, nullptr, nullptr, B_ * K_, TOK_, 768);

  logits_kernel<<<B_ * K_, 64, 0, stream>>>(lat, img_feature_proj, logits);
  select_kernel<<<B_, 64, 0, stream>>>(logits, lat, (float*)d_out,
                                       (float*)d_out + (size_t)B_ * TOPK_ * TOK_);
}

// Round 17
// 2606.847 us; speedup vs baseline: 1.1641x; 1.0351x over previous
//
#include <hip/hip_runtime.h>
#include <math.h>

// Problem constants
#define B_    128
#define P_    197
#define D_    768
#define TOK_  512
#define K_    16
#define TOPK_ 8
#define L_    2
#define H_    12
#define HD_   64
#define NTOK  213            // K_ + P_
#define MROWS (B_ * NTOK)    // 27264
#define QKVN  2304           // fused q|k|v row width

typedef _Float16 f16;
typedef __attribute__((ext_vector_type(8))) _Float16 f16x8;
typedef __attribute__((ext_vector_type(4))) _Float16 f16x4;
typedef __attribute__((ext_vector_type(4))) float f32x4;

__device__ __forceinline__ void gload_lds16(const void* g, void* l) {
  __builtin_amdgcn_global_load_lds(
      (const __attribute__((address_space(1))) unsigned int*)g,
      (__attribute__((address_space(3))) unsigned int*)l, 16, 0, 0);
}

__device__ __forceinline__ float wred_sum(float v) {
#pragma unroll
  for (int o = 32; o > 0; o >>= 1) v += __shfl_xor(v, o);
  return v;
}
__device__ __forceinline__ float wred_max(float v) {
#pragma unroll
  for (int o = 32; o > 0; o >>= 1) v = fmaxf(v, __shfl_xor(v, o));
  return v;
}
__device__ __forceinline__ float red16_max(float v) {
#pragma unroll
  for (int o = 8; o > 0; o >>= 1) v = fmaxf(v, __shfl_xor(v, o));
  return v;
}
__device__ __forceinline__ float red16_sum(float v) {
#pragma unroll
  for (int o = 8; o > 0; o >>= 1) v += __shfl_xor(v, o);
  return v;
}

// ---------------- concat: x = [templates broadcast | img_patch_feats] ----
__global__ __launch_bounds__(256) void concat_kernel(
    const float* __restrict__ tpl, const float* __restrict__ patches,
    float* __restrict__ x) {
  size_t i = (size_t)blockIdx.x * 256 + threadIdx.x;  // one float4 each
  const size_t total = (size_t)MROWS * (D_ / 4);
  if (i >= total) return;
  size_t row = i / (D_ / 4);
  int c = (int)(i % (D_ / 4)) * 4;
  size_t b = row / NTOK;
  int n = (int)(row % NTOK);
  float4 v;
  if (n < K_) v = *(const float4*)(tpl + (size_t)n * D_ + c);
  else        v = *(const float4*)(patches + ((size_t)b * P_ + (n - K_)) * D_ + c);
  *(float4*)(x + row * D_ + c) = v;
}

// ---------------- LayerNorm: 4 rows/block (4 waves), f16 hi/lo out --------
__global__ __launch_bounds__(256) void ln_split_kernel(
    const float* __restrict__ x, const float* __restrict__ w,
    const float* __restrict__ b, f16* __restrict__ yh, f16* __restrict__ yl,
    int nrows) {
  int row = blockIdx.x * 4 + (threadIdx.x >> 6);
  if (row >= nrows) return;
  int lane = threadIdx.x & 63;
  const float* xr = x + (size_t)row * D_;
  float4 v[3];
#pragma unroll
  for (int j = 0; j < 3; ++j) v[j] = *(const float4*)(xr + j * 256 + lane * 4);
  float s = 0.f, sq = 0.f;
#pragma unroll
  for (int j = 0; j < 3; ++j) {
    s += v[j].x + v[j].y + v[j].z + v[j].w;
    sq = fmaf(v[j].x, v[j].x, sq); sq = fmaf(v[j].y, v[j].y, sq);
    sq = fmaf(v[j].z, v[j].z, sq); sq = fmaf(v[j].w, v[j].w, sq);
  }
#pragma unroll
  for (int o = 32; o > 0; o >>= 1) { s += __shfl_xor(s, o); sq += __shfl_xor(sq, o); }
  float mean = s * (1.f / D_);
  float var = sq * (1.f / D_) - mean * mean;
  float rs = rsqrtf(var + 1e-5f);
#pragma unroll
  for (int j = 0; j < 3; ++j) {
    int col = j * 256 + lane * 4;
    float4 wv = *(const float4*)(w + col);
    float4 bv = *(const float4*)(b + col);
    float o0 = (v[j].x - mean) * rs * wv.x + bv.x;
    float o1 = (v[j].y - mean) * rs * wv.y + bv.y;
    float o2 = (v[j].z - mean) * rs * wv.z + bv.z;
    float o3 = (v[j].w - mean) * rs * wv.w + bv.w;
    f16x4 hi = {(f16)o0, (f16)o1, (f16)o2, (f16)o3};
    f16x4 lo = {(f16)(o0 - (float)hi[0]), (f16)(o1 - (float)hi[1]),
                (f16)(o2 - (float)hi[2]), (f16)(o3 - (float)hi[3])};
    *(f16x4*)&yh[(size_t)row * D_ + col] = hi;
    *(f16x4*)&yl[(size_t)row * D_ + col] = lo;
  }
}

// -------- weight transpose + f16 hi/lo split: W[K][N] -> Wt[N][K] --------
__global__ __launch_bounds__(256) void transpose_split(
    const float* __restrict__ W, f16* __restrict__ Wh, f16* __restrict__ Wl,
    int Kd, int Nd) {
  __shared__ float t[32][33];
  const int n0 = blockIdx.x * 32, k0 = blockIdx.y * 32;
  const int tx = threadIdx.x & 31, ty = threadIdx.x >> 5;  // 32 x 8
#pragma unroll
  for (int j = 0; j < 4; ++j)
    t[ty + 8 * j][tx] = W[(size_t)(k0 + ty + 8 * j) * Nd + n0 + tx];
  __syncthreads();
#pragma unroll
  for (int j = 0; j < 4; ++j) {
    float v = t[tx][ty + 8 * j];
    f16 hi = (f16)v;
    size_t off = (size_t)(n0 + ty + 8 * j) * Kd + k0 + tx;
    Wh[off] = hi;
    Wl[off] = (f16)(v - (float)hi);
  }
}

// -------- combine q_b (768) and kv_b (1536) into qkv_b (2304) -------------
__global__ __launch_bounds__(256) void combine_bias(
    const float* __restrict__ qb, const float* __restrict__ kvb,
    float* __restrict__ out) {
  int i = blockIdx.x * 256 + threadIdx.x;
  if (i < QKVN) out[i] = (i < D_) ? qb[i] : kvb[i - D_];
}

// ------- split-f16 MFMA GEMM: C = act(A @ Wt^T + bias) [+C] --------------
// BM=64, BN=128, BK=32, 256 thr = 4 waves (1M x 4N, 64x32 per wave).
// 2-phase dbuf at 48 KB -> 3 blocks/CU (occupancy lever vs R13's 64 KB/2).
// Counted vmcnt(6), chunk swizzle, band(8 N-tiles)+XCD bijective mapping.
// acc += Ah*Wh + Ah*Wl + Al*Wh  (3-pass, near-fp32 — numerics-mandatory).
template <int ACT, bool RESID, bool OUTSPLIT>
__global__ __launch_bounds__(256) void gemm_split(
    const f16* __restrict__ Ah, const f16* __restrict__ Al,
    const f16* __restrict__ Wh, const f16* __restrict__ Wl,
    const float* __restrict__ bias, float* __restrict__ Cf,
    f16* __restrict__ Ch, f16* __restrict__ Cl, int M, int N, int K) {
  // per buffer (f16 units): Ah [0,2048) Al [2048,4096) Wh [4096,8192)
  // Wl [8192,12288). 2 buffers x 24 KB = 48 KB.
  __shared__ __align__(16) f16 S[2 * 12288];
  const int tid = threadIdx.x;
  // --- XCD-aware bijective chunk remap (8 XCDs, round-robin dispatch) ---
  const int nwg = gridDim.x;
  const int bid = blockIdx.x;
  const int xcd = bid & 7, idx = bid >> 3;
  const int qc = nwg >> 3, rc = nwg & 7;
  const int o = (xcd < rc ? xcd * (qc + 1) : rc * (qc + 1) + (xcd - rc) * qc) + idx;
  // --- band-ordered tile mapping (bands of 8 N-tiles, m-major inside) ---
  const int ntx = N >> 7;
  const int mt = nwg / ntx;
  const int fullArea = (ntx >> 3) * (mt << 3);
  int band, r, bw;
  if (o < fullArea) { band = o / (mt << 3); r = o - band * (mt << 3); bw = 8; }
  else             { band = ntx >> 3;      r = o - fullArea;          bw = ntx & 7; }
  const int bn = (band * 8 + r % bw) * 128;
  const int bm = (r / bw) * 64;

  const int w = tid >> 6, lane = tid & 63;
  const int wn = w * 32;                    // wave's N-offset (1M x 4N)
  const int fr = lane & 15, kg = lane >> 4;
  f32x4 acc[4][2];
  const f32x4 z = {0.f, 0.f, 0.f, 0.f};
#pragma unroll
  for (int i = 0; i < 4; ++i)
#pragma unroll
    for (int j = 0; j < 2; ++j) acc[i][j] = z;
  const int c_l  = (tid & 3) ^ ((tid >> 3) & 3);   // logical k-chunk fetched
  const int cswz = (kg ^ ((fr >> 1) & 3)) * 8;     // physical chunk on read

  auto STAGE = [&](int k0, int buf) {
    f16* base = &S[buf * 12288];
    {   // A planes: 64 rows x 4 chunks = 256 slots, 1 load/thread/plane
      int row = tid >> 2;
      int arow = bm + row; if (arow >= M) arow = M - 1;   // stores guarded
      size_t ga = (size_t)arow * K + k0 + c_l * 8;
      gload_lds16(Ah + ga, base + tid * 8);
      gload_lds16(Al + ga, base + 2048 + tid * 8);
    }
#pragma unroll
    for (int rep = 0; rep < 2; ++rep) {   // W planes: 128 rows x 4 chunks
      int s = tid + rep * 256;
      int row = s >> 2;
      int lch = (s & 3) ^ ((s >> 3) & 3);
      size_t gw = (size_t)(bn + row) * K + k0 + lch * 8;
      gload_lds16(Wh + gw, base + 4096 + s * 8);
      gload_lds16(Wl + gw, base + 8192 + s * 8);
    }
  };
  auto COMPUTE = [&](int buf) {
    const f16* base = &S[buf * 12288];
    f16x8 ah[4], al[4], bh[2], bl[2];
#pragma unroll
    for (int i = 0; i < 4; ++i) {
      int ar = (i * 16 + fr) * 32 + cswz;
      ah[i] = *(const f16x8*)(base + ar);
      al[i] = *(const f16x8*)(base + 2048 + ar);
    }
#pragma unroll
    for (int j = 0; j < 2; ++j) {
      int br = (wn + j * 16 + fr) * 32 + cswz;
      bh[j] = *(const f16x8*)(base + 4096 + br);
      bl[j] = *(const f16x8*)(base + 8192 + br);
    }
#pragma unroll
    for (int i = 0; i < 4; ++i)
#pragma unroll
      for (int j = 0; j < 2; ++j) {
        acc[i][j] = __builtin_amdgcn_mfma_f32_16x16x32_f16(ah[i], bh[j], acc[i][j], 0, 0, 0);
        acc[i][j] = __builtin_amdgcn_mfma_f32_16x16x32_f16(ah[i], bl[j], acc[i][j], 0, 0, 0);
        acc[i][j] = __builtin_amdgcn_mfma_f32_16x16x32_f16(al[i], bh[j], acc[i][j], 0, 0, 0);
      }
  };

  const int nt = K / 32;
  int cur = 0;
  STAGE(0, 0);
  for (int t = 0; t < nt - 1; ++t) {
    STAGE((t + 1) * 32, cur ^ 1);
    asm volatile("s_waitcnt vmcnt(6)" ::: "memory");
    __builtin_amdgcn_s_barrier();
    __builtin_amdgcn_sched_barrier(0);
    COMPUTE(cur);
    __builtin_amdgcn_s_barrier();
    cur ^= 1;
  }
  asm volatile("s_waitcnt vmcnt(0)" ::: "memory");
  __builtin_amdgcn_s_barrier();
  __builtin_amdgcn_sched_barrier(0);
  COMPUTE(cur);

  // epilogue: D[row=kg*4+rg][col=fr] per 16x16 fragment (m89 layout)
#pragma unroll
  for (int j = 0; j < 2; ++j) {
    const int gc = bn + wn + j * 16 + fr;
    const float bv = bias[gc];
#pragma unroll
    for (int i = 0; i < 4; ++i) {
#pragma unroll
      for (int rg = 0; rg < 4; ++rg) {
        int gr = bm + i * 16 + kg * 4 + rg;
        if (gr < M) {
          float val = acc[i][j][rg] + bv;
          if (ACT == 1) val = fmaxf(val, 0.f);
          if (ACT == 2) val = 1.f / (1.f + expf(-val));
          size_t off = (size_t)gr * N + gc;
          if (OUTSPLIT) {
            f16 hi = (f16)val;
            Ch[off] = hi;
            Cl[off] = (f16)(val - (float)hi);
          } else {
            if (RESID) val += Cf[off];
            Cf[off] = val;
          }
        }
      }
    }
  }
}

// ---------------- MFMA flash attention, split-f16 3-pass ------------------
// Q/K/V read from fused qkv buffer [row][2304]: q +0, k +768, v +1536.
__global__ __launch_bounds__(256) void attn_mfma(
    const f16* __restrict__ QKVh, const f16* __restrict__ QKVl,
    f16* __restrict__ Oh, f16* __restrict__ Ol) {
  __shared__ __align__(16) f16 Ksh[64][64];
  __shared__ __align__(16) f16 Ksl[64][64];
  __shared__ __align__(16) f16 Vsh[64][64];
  __shared__ __align__(16) f16 Vsl[64][64];
  __shared__ __align__(16) f16 Psh[4][32][64];
  __shared__ __align__(16) f16 Psl[4][32][64];
  const int b = blockIdx.x, h = blockIdx.y, zb = blockIdx.z;
  const int tid = threadIdx.x, w = tid >> 6, lane = tid & 63;
  const int fr = lane & 15, kg = lane >> 4;
  const int qbase = zb * 128 + w * 32;
  const size_t rowbase = (size_t)b * NTOK;
  const int hoff = h * HD_;
  const f32x4 z4 = {0.f, 0.f, 0.f, 0.f};

  f16x8 qfh[2][2], qfl[2][2];
#pragma unroll
  for (int mf = 0; mf < 2; ++mf) {
    int qr = qbase + mf * 16 + fr; if (qr >= NTOK) qr = NTOK - 1;
    const size_t ro = (rowbase + qr) * QKVN + hoff;
#pragma unroll
    for (int ks = 0; ks < 2; ++ks) {
      qfh[mf][ks] = *(const f16x8*)&QKVh[ro + ks * 32 + kg * 8];
      qfl[mf][ks] = *(const f16x8*)&QKVl[ro + ks * 32 + kg * 8];
    }
  }

  f32x4 oacc[2][4];
#pragma unroll
  for (int mf = 0; mf < 2; ++mf)
#pragma unroll
    for (int df = 0; df < 4; ++df) oacc[mf][df] = z4;
  float m_r[2][4], l_r[2][4];
#pragma unroll
  for (int mf = 0; mf < 2; ++mf)
#pragma unroll
    for (int rg = 0; rg < 4; ++rg) { m_r[mf][rg] = -INFINITY; l_r[mf][rg] = 0.f; }

  for (int t = 0; t < 4; ++t) {
    const int t0 = t * 64;
    __syncthreads();
#pragma unroll
    for (int s = 0; s < 2; ++s) {
      int slot = tid + s * 256;
      int trow = slot >> 3, pch = slot & 7;
      int lch = pch ^ (trow & 7);
      int tok = t0 + trow; if (tok >= NTOK) tok = NTOK - 1;
      size_t src = (rowbase + tok) * (size_t)QKVN + D_ + hoff + lch * 8;
      gload_lds16(QKVh + src, (char*)&Ksh[0][0] + s * 4096 + w * 1024);
      gload_lds16(QKVl + src, (char*)&Ksl[0][0] + s * 4096 + w * 1024);
    }
    {
      int tloc = tid & 63, dg = tid >> 6;
      int tok = t0 + tloc; if (tok >= NTOK) tok = NTOK - 1;
      size_t src = (rowbase + tok) * (size_t)QKVN + 2 * D_ + hoff + dg * 16;
      f16x8 v0h = *(const f16x8*)&QKVh[src];
      f16x8 v1h = *(const f16x8*)&QKVh[src + 8];
      f16x8 v0l = *(const f16x8*)&QKVl[src];
      f16x8 v1l = *(const f16x8*)&QKVl[src + 8];
      int ch = tloc >> 3, pos = tloc & 7;
#pragma unroll
      for (int i = 0; i < 8; ++i) {
        int d0 = dg * 16 + i, d1 = d0 + 8;
        Vsh[d0][((ch ^ (d0 & 7)) << 3) | pos] = v0h[i];
        Vsh[d1][((ch ^ (d1 & 7)) << 3) | pos] = v1h[i];
        Vsl[d0][((ch ^ (d0 & 7)) << 3) | pos] = v0l[i];
        Vsl[d1][((ch ^ (d1 & 7)) << 3) | pos] = v1l[i];
      }
    }
    __syncthreads();
    f16x8 kbh[4][2], kbl[4][2];
#pragma unroll
    for (int nf = 0; nf < 4; ++nf)
#pragma unroll
      for (int ks = 0; ks < 2; ++ks) {
        int phys = (((ks * 4 + kg) ^ (fr & 7))) * 8;
        kbh[nf][ks] = *(const f16x8*)&Ksh[nf * 16 + fr][phys];
        kbl[nf][ks] = *(const f16x8*)&Ksl[nf * 16 + fr][phys];
      }
    f32x4 sacc[2][4];
#pragma unroll
    for (int mf = 0; mf < 2; ++mf)
#pragma unroll
      for (int nf = 0; nf < 4; ++nf) sacc[mf][nf] = z4;
#pragma unroll
    for (int ks = 0; ks < 2; ++ks)
#pragma unroll
      for (int mf = 0; mf < 2; ++mf)
#pragma unroll
        for (int nf = 0; nf < 4; ++nf) {
          sacc[mf][nf] = __builtin_amdgcn_mfma_f32_16x16x32_f16(qfh[mf][ks], kbh[nf][ks], sacc[mf][nf], 0, 0, 0);
          sacc[mf][nf] = __builtin_amdgcn_mfma_f32_16x16x32_f16(qfh[mf][ks], kbl[nf][ks], sacc[mf][nf], 0, 0, 0);
          sacc[mf][nf] = __builtin_amdgcn_mfma_f32_16x16x32_f16(qfl[mf][ks], kbh[nf][ks], sacc[mf][nf], 0, 0, 0);
        }
#pragma unroll
    for (int nf = 0; nf < 4; ++nf) {
      bool valid = (t0 + nf * 16 + fr) < NTOK;
#pragma unroll
      for (int mf = 0; mf < 2; ++mf)
#pragma unroll
        for (int rg = 0; rg < 4; ++rg)
          sacc[mf][nf][rg] = valid ? sacc[mf][nf][rg] * 0.125f : -INFINITY;
    }
#pragma unroll
    for (int mf = 0; mf < 2; ++mf) {
      float scl[4];
#pragma unroll
      for (int rg = 0; rg < 4; ++rg) {
        float mx = fmaxf(fmaxf(sacc[mf][0][rg], sacc[mf][1][rg]),
                         fmaxf(sacc[mf][2][rg], sacc[mf][3][rg]));
        mx = red16_max(mx);
        float nm = fmaxf(m_r[mf][rg], mx);
        scl[rg] = __expf(m_r[mf][rg] - nm);
        m_r[mf][rg] = nm;
        float ts = 0.f;
        int qlc = mf * 16 + kg * 4 + rg;
#pragma unroll
        for (int nf = 0; nf < 4; ++nf) {
          float p = __expf(sacc[mf][nf][rg] - nm);
          ts += p;
          f16 ph = (f16)p;
          int tl = nf * 16 + fr;
          int off = (((tl >> 3) ^ (qlc & 7)) << 3) | (tl & 7);
          Psh[w][qlc][off] = ph;
          Psl[w][qlc][off] = (f16)(p - (float)ph);
        }
        ts = red16_sum(ts);
        l_r[mf][rg] = l_r[mf][rg] * scl[rg] + ts;
      }
#pragma unroll
      for (int df = 0; df < 4; ++df)
#pragma unroll
        for (int rg = 0; rg < 4; ++rg)
          oacc[mf][df][rg] *= scl[rg];
    }
    f16x8 vbh[4][2], vbl[4][2];
#pragma unroll
    for (int df = 0; df < 4; ++df)
#pragma unroll
      for (int ks = 0; ks < 2; ++ks) {
        int phys = (((ks * 4 + kg) ^ (fr & 7))) * 8;
        vbh[df][ks] = *(const f16x8*)&Vsh[df * 16 + fr][phys];
        vbl[df][ks] = *(const f16x8*)&Vsl[df * 16 + fr][phys];
      }
    f16x8 pah[2][2], pal[2][2];
#pragma unroll
    for (int mf = 0; mf < 2; ++mf)
#pragma unroll
      for (int ks = 0; ks < 2; ++ks) {
        int phys = (((ks * 4 + kg) ^ (fr & 7))) * 8;
        pah[mf][ks] = *(const f16x8*)&Psh[w][mf * 16 + fr][phys];
        pal[mf][ks] = *(const f16x8*)&Psl[w][mf * 16 + fr][phys];
      }
#pragma unroll
    for (int ks = 0; ks < 2; ++ks)
#pragma unroll
      for (int mf = 0; mf < 2; ++mf)
#pragma unroll
        for (int df = 0; df < 4; ++df) {
          oacc[mf][df] = __builtin_amdgcn_mfma_f32_16x16x32_f16(pah[mf][ks], vbh[df][ks], oacc[mf][df], 0, 0, 0);
          oacc[mf][df] = __builtin_amdgcn_mfma_f32_16x16x32_f16(pah[mf][ks], vbl[df][ks], oacc[mf][df], 0, 0, 0);
          oacc[mf][df] = __builtin_amdgcn_mfma_f32_16x16x32_f16(pal[mf][ks], vbh[df][ks], oacc[mf][df], 0, 0, 0);
        }
  }
#pragma unroll
  for (int mf = 0; mf < 2; ++mf)
#pragma unroll
    for (int rg = 0; rg < 4; ++rg) {
      int qr = qbase + mf * 16 + kg * 4 + rg;
      if (qr < NTOK) {
        float inv = 1.f / l_r[mf][rg];
        size_t ro = (rowbase + qr) * D_ + hoff;
#pragma unroll
        for (int df = 0; df < 4; ++df) {
          float val = oacc[mf][df][rg] * inv;
          f16 hi = (f16)val;
          Oh[ro + df * 16 + fr] = hi;
          Ol[ro + df * 16 + fr] = (f16)(val - (float)hi);
        }
      }
    }
}

// ---------- gather x[:, :16, :] -> f16 hi/lo planes [2048][768] -----------
__global__ __launch_bounds__(256) void gather_split(
    const float* __restrict__ x, f16* __restrict__ oh, f16* __restrict__ ol) {
  int idx = blockIdx.x * 256 + threadIdx.x;
  if (idx >= B_ * K_ * (D_ / 4)) return;
  int row = idx / (D_ / 4);
  int c4 = (idx % (D_ / 4)) * 4;
  int b = row >> 4, k = row & 15;
  const float* src = x + ((size_t)(b * NTOK + k)) * D_ + c4;
  f16x4 hi, lo;
#pragma unroll
  for (int i = 0; i < 4; ++i) {
    float v = src[i];
    hi[i] = (f16)v;
    lo[i] = (f16)(v - (float)hi[i]);
  }
  *(f16x4*)&oh[(size_t)row * D_ + c4] = hi;
  *(f16x4*)&ol[(size_t)row * D_ + c4] = lo;
}

// ---------------- logits[b,k] = dot(lat[b,k,:], proj[b,:]) ----------------
__global__ __launch_bounds__(64) void logits_kernel(
    const float* __restrict__ lat, const float* __restrict__ proj,
    float* __restrict__ logits) {
  int bk = blockIdx.x;
  int b = bk >> 4;
  int lane = threadIdx.x;
  const float* lr = lat + (size_t)bk * TOK_;
  const float* pr = proj + (size_t)b * TOK_;
  float s = 0.f;
#pragma unroll
  for (int i = 0; i < 8; ++i) s = fmaf(lr[lane + 64 * i], pr[lane + 64 * i], s);
  s = wred_sum(s);
  if (lane == 0) logits[bk] = s;
}

// ---------------- softmax + topk select + normalize (1 wave per b) --------
__global__ __launch_bounds__(64) void select_kernel(
    const float* __restrict__ logits, const float* __restrict__ lat,
    float* __restrict__ out_sel, float* __restrict__ out_numr) {
  const int b = blockIdx.x;
  const int lane = threadIdx.x;
  __shared__ float aw_s[16];
  __shared__ int sel_id_s[8];
  __shared__ int numr_s;
  float v = (lane < 16) ? logits[b * 16 + lane] : -INFINITY;
  float mx = wred_max(v);
  float e = (lane < 16) ? expf(v - mx) : 0.f;
  float sum = wred_sum(e);
  float aw = e / sum;
  if (lane < 16) aw_s[lane] = aw;
  unsigned long long ball = __ballot(lane < 16 && aw > 0.05f);
  int counts = __popcll(ball);
  __syncthreads();
  if (lane == 0) {
    int num_r = counts < 1 ? 1 : (counts > TOPK_ ? TOPK_ : counts);
    numr_s = num_r;
    bool used[16];
#pragma unroll
    for (int i = 0; i < 16; ++i) used[i] = false;
    int sorted_idx[8];
    for (int j = 0; j < 8; ++j) {   // descending top-8 (ties: lowest index)
      float bv = -INFINITY; int bi = 0;
      for (int i = 0; i < 16; ++i)
        if (!used[i] && aw_s[i] > bv) { bv = aw_s[i]; bi = i; }
      used[bi] = true;
      sorted_idx[j] = bi;
    }
    int keys[8];
    for (int j = 0; j < 8; ++j) keys[j] = (j < num_r) ? sorted_idx[j] : (16 + j);
    bool kused[8];
    for (int j = 0; j < 8; ++j) kused[j] = false;
    for (int slot = 0; slot < 8; ++slot) {  // perm = argsort(keys), gather
      int bk = 1 << 30, bj = 0;
      for (int j = 0; j < 8; ++j)
        if (!kused[j] && keys[j] < bk) { bk = keys[j]; bj = j; }
      kused[bj] = true;
      sel_id_s[slot] = sorted_idx[bj];
    }
  }
  __syncthreads();
  for (int j = 0; j < 8; ++j) {
    int id = sel_id_s[j];
    const float* row = lat + ((size_t)b * 16 + id) * TOK_;
    float vals[8];
    float sq = 0.f;
#pragma unroll
    for (int i = 0; i < 8; ++i) {
      vals[i] = row[lane + 64 * i];
      sq = fmaf(vals[i], vals[i], sq);
    }
    sq = wred_sum(sq);
    float inv = 1.f / fmaxf(sqrtf(sq), 1e-12f);
#pragma unroll
    for (int i = 0; i < 8; ++i)
      out_sel[((size_t)b * 8 + j) * TOK_ + lane + 64 * i] = vals[i] * inv;
  }
  if (lane == 0) out_numr[b] = (float)numr_s;
}

// ---------------- host launcher -------------------------------------------
extern "C" void kernel_launch(void* const* d_in, const int* in_sizes, int n_in,
                              void* d_out, int out_size, void* d_ws, size_t ws_size,
                              hipStream_t stream) {
  const float* img_feature_proj = (const float*)d_in[0];
  const float* img_patch_feats  = (const float*)d_in[1];
  const float* templates        = (const float*)d_in[2];
  const float* ln1_w  = (const float*)d_in[3];
  const float* ln1_b  = (const float*)d_in[4];
  const float* q_w    = (const float*)d_in[5];
  const float* q_b    = (const float*)d_in[6];
  const float* kv_w   = (const float*)d_in[7];
  const float* kv_b   = (const float*)d_in[8];
  const float* proj_w = (const float*)d_in[9];
  const float* proj_b = (const float*)d_in[10];
  const float* ln2_w  = (const float*)d_in[11];
  const float* ln2_b  = (const float*)d_in[12];
  const float* fc1_w  = (const float*)d_in[13];
  const float* fc1_b  = (const float*)d_in[14];
  const float* fc2_w  = (const float*)d_in[15];
  const float* fc2_b  = (const float*)d_in[16];
  const float* att_fc_w = (const float*)d_in[17];
  const float* att_fc_b = (const float*)d_in[18];

  // ---- fixed workspace ----
  char* ws = (char*)d_ws;
  const size_t XB = (size_t)MROWS * D_ * 4;              // 83,755,008 B
  float* x_f = (float*)ws;  ws += XB;                    // residual fp32
  auto alloc_f16 = [&](size_t n) { f16* p = (f16*)ws; ws += n * 2; return p; };
  f16* wqkv_h = alloc_f16((size_t)QKVN * 768);
  f16* wqkv_l = alloc_f16((size_t)QKVN * 768);
  f16* wp_h   = alloc_f16((size_t)768 * 768);
  f16* wp_l   = alloc_f16((size_t)768 * 768);
  f16* wf1_h  = alloc_f16((size_t)1536 * 768);
  f16* wf1_l  = alloc_f16((size_t)1536 * 768);
  f16* wf2_h  = alloc_f16((size_t)768 * 1536);
  f16* wf2_l  = alloc_f16((size_t)768 * 1536);
  f16* awt_h  = alloc_f16((size_t)512 * 768);
  f16* awt_l  = alloc_f16((size_t)512 * 768);
  f16* lat_h  = alloc_f16((size_t)2048 * 768);
  f16* lat_l  = alloc_f16((size_t)2048 * 768);
  float* qkv_b  = (float*)ws; ws += QKVN * 4;
  float* lat    = (float*)ws; ws += (size_t)2048 * 512 * 4;
  float* logits = (float*)ws; ws += 8192;
  const size_t fixed_bytes = (size_t)(ws - (char*)d_ws);

  // ---- adaptive batch-chunk: h planes 4B + qkv planes 12B per elem-row ----
  int NB = B_;
  while (NB > 1) {
    size_t CHE = (size_t)NB * NTOK * D_;
    if (fixed_bytes + 16 * CHE <= ws_size) break;
    NB >>= 1;
  }
  const size_t CHE = (size_t)NB * NTOK * D_;
  f16* h_h   = (f16*)ws;                 // CHE
  f16* h_l   = h_h + CHE;                // CHE
  f16* qkvh  = h_l + CHE;                // 3*CHE
  f16* qkvl  = qkvh + 3 * CHE;           // 3*CHE
  f16* fc1o_h = qkvh;                    // alias: 2*CHE
  f16* fc1o_l = qkvl;                    // alias: 2*CHE

  // ---- concat ----
  {
    size_t total = (size_t)MROWS * (D_ / 4);
    concat_kernel<<<(unsigned)((total + 255) / 256), 256, 0, stream>>>(
        templates, img_patch_feats, x_f);
  }
  transpose_split<<<dim3(16, 24), 256, 0, stream>>>(att_fc_w, awt_h, awt_l, 768, 512);

  const int nchunks = B_ / NB;
  for (int l = 0; l < L_; ++l) {
    transpose_split<<<dim3(24, 24), 256, 0, stream>>>(q_w + (size_t)l * 768 * 768, wqkv_h, wqkv_l, 768, 768);
    transpose_split<<<dim3(48, 24), 256, 0, stream>>>(kv_w + (size_t)l * 768 * 1536,
        wqkv_h + (size_t)768 * 768, wqkv_l + (size_t)768 * 768, 768, 1536);
    combine_bias<<<(QKVN + 255) / 256, 256, 0, stream>>>(q_b + l * D_, kv_b + l * 1536, qkv_b);
    transpose_split<<<dim3(24, 24), 256, 0, stream>>>(proj_w + (size_t)l * 768 * 768, wp_h, wp_l, 768, 768);
    transpose_split<<<dim3(48, 24), 256, 0, stream>>>(fc1_w + (size_t)l * 768 * 1536, wf1_h, wf1_l, 768, 1536);
    transpose_split<<<dim3(24, 48), 256, 0, stream>>>(fc2_w + (size_t)l * 1536 * 768, wf2_h, wf2_l, 1536, 768);
    for (int c = 0; c < nchunks; ++c) {
      const int b0 = c * NB;
      const int Rc = NB * NTOK;
      const int mt = (Rc + 63) / 64;
      float* xc = x_f + (size_t)b0 * NTOK * D_;
      ln_split_kernel<<<(Rc + 3) / 4, 256, 0, stream>>>(xc, ln1_w + l * D_, ln1_b + l * D_, h_h, h_l, Rc);
      gemm_split<0, false, true><<<(QKVN / 128) * mt, 256, 0, stream>>>(
          h_h, h_l, wqkv_h, wqkv_l, qkv_b, nullptr, qkvh, qkvl, Rc, QKVN, 768);
      attn_mfma<<<dim3(NB, H_, 2), 256, 0, stream>>>(qkvh, qkvl, h_h, h_l);
      gemm_split<0, true, false><<<6 * mt, 256, 0, stream>>>(
          h_h, h_l, wp_h, wp_l, proj_b + l * D_, xc, nullptr, nullptr, Rc, 768, 768);
      ln_split_kernel<<<(Rc + 3) / 4, 256, 0, stream>>>(xc, ln2_w + l * D_, ln2_b + l * D_, h_h, h_l, Rc);
      gemm_split<1, false, true><<<12 * mt, 256, 0, stream>>>(
          h_h, h_l, wf1_h, wf1_l, fc1_b + l * 1536, nullptr, fc1o_h, fc1o_l, Rc, 1536, 768);
      gemm_split<0, true, false><<<6 * mt, 256, 0, stream>>>(
          fc1o_h, fc1o_l, wf2_h, wf2_l, fc2_b + l * D_, xc, nullptr, nullptr, Rc, 768, 1536);
    }
  }

  gather_split<<<(B_ * K_ * (D_ / 4) + 255) / 256, 256, 0, stream>>>(x_f, lat_h, lat_l);
  gemm_split<2, false, false><<<4 * 32, 256, 0, stream>>>(
      lat_h, lat_l, awt_h, awt_l, att_fc_b, lat, nullptr, nullptr, B_ * K_, TOK_, 768);

  logits_kernel<<<B_ * K_, 64, 0, stream>>>(lat, img_feature_proj, logits);
  select_kernel<<<B_, 64, 0, stream>>>(logits, lat, (float*)d_out,
                                       (float*)d_out + (size_t)B_ * TOPK_ * TOK_);
}